// Round 1
// baseline (2786.491 us; speedup 1.0000x reference)
//
#include <hip/hip_runtime.h>
#include <math.h>

#define NH 16
#define DH 64
#define MDIM 64
#define DMODEL 1024
#define FDIM 4096
#define BATCH 2
#define SEQ 2048
#define NROWS (BATCH*SEQ)   // 4096

__device__ __forceinline__ float gelu_f(float v) {
    return 0.5f * v * (1.0f + erff(v * 0.70710678118654752f));
}

// ---------------- generic GEMM: C = act(A@W + bias) ----------------
// A: (rows, K) row-major; W: (K, cols) row-major; C: (rows, cols)
// tile 64x64, BK=16, 256 threads, 4x4 micro-tile. ACT: 0 none, 1 gelu.
template<int ACT>
__global__ __launch_bounds__(256)
void gemm_kernel(const float* __restrict__ A, const float* __restrict__ W,
                 const float* __restrict__ bias, float* __restrict__ C,
                 int K, int cols) {
    __shared__ float As[16][65];   // [kk][row] transposed, +1 pad
    __shared__ float Ws[16][68];   // [kk][col], +4 pad (keeps float4 alignment)
    const int t  = threadIdx.x;
    const int tc = t & 15;         // micro col group
    const int tr = t >> 4;         // micro row group
    const int n0 = blockIdx.x * 64;
    const int i0 = blockIdx.y * 64;
    const int ar = t >> 2;               // 0..63 A row
    const int ac = (t & 3) << 2;         // 0,4,8,12
    const int wr = t >> 4;               // 0..15 W row
    const int wc = (t & 15) << 2;        // 0..60
    const float* Ap = A + (size_t)(i0 + ar) * K + ac;
    const float* Wp = W + (size_t)wr * cols + n0 + wc;

    float acc[4][4] = {};
    for (int k0 = 0; k0 < K; k0 += 16) {
        float4 a4 = *(const float4*)(Ap + k0);
        float4 w4 = *(const float4*)(Wp + (size_t)k0 * cols);
        __syncthreads();   // protect previous iteration's reads
        As[ac + 0][ar] = a4.x;
        As[ac + 1][ar] = a4.y;
        As[ac + 2][ar] = a4.z;
        As[ac + 3][ar] = a4.w;
        *(float4*)&Ws[wr][wc] = w4;
        __syncthreads();
#pragma unroll
        for (int kk = 0; kk < 16; ++kk) {
            float a0 = As[kk][tr * 4 + 0];
            float a1 = As[kk][tr * 4 + 1];
            float a2 = As[kk][tr * 4 + 2];
            float a3 = As[kk][tr * 4 + 3];
            float4 b = *(const float4*)&Ws[kk][tc * 4];
            acc[0][0] += a0 * b.x; acc[0][1] += a0 * b.y; acc[0][2] += a0 * b.z; acc[0][3] += a0 * b.w;
            acc[1][0] += a1 * b.x; acc[1][1] += a1 * b.y; acc[1][2] += a1 * b.z; acc[1][3] += a1 * b.w;
            acc[2][0] += a2 * b.x; acc[2][1] += a2 * b.y; acc[2][2] += a2 * b.z; acc[2][3] += a2 * b.w;
            acc[3][0] += a3 * b.x; acc[3][1] += a3 * b.y; acc[3][2] += a3 * b.z; acc[3][3] += a3 * b.w;
        }
    }
    float4 bv = make_float4(0.f, 0.f, 0.f, 0.f);
    if (bias) bv = *(const float4*)(bias + n0 + tc * 4);
#pragma unroll
    for (int i = 0; i < 4; ++i) {
        float4 o;
        o.x = acc[i][0] + bv.x;
        o.y = acc[i][1] + bv.y;
        o.z = acc[i][2] + bv.z;
        o.w = acc[i][3] + bv.w;
        if (ACT == 1) { o.x = gelu_f(o.x); o.y = gelu_f(o.y); o.z = gelu_f(o.z); o.w = gelu_f(o.w); }
        *(float4*)(C + (size_t)(i0 + tr * 4 + i) * cols + n0 + tc * 4) = o;
    }
}

// ------------- per-head projection: out[b,h,s,m] = sum_d X[b,s,h*64+d]*Mk[h,d,m] -------------
__global__ __launch_bounds__(256)
void headproj_kernel(const float* __restrict__ X, const float* __restrict__ Mk,
                     float* __restrict__ out) {
    __shared__ float Qs[64][65];   // [d][s] transposed
    __shared__ float Ms[64][68];   // [d][m]
    const int s0 = blockIdx.x * 64;
    const int h  = blockIdx.y;
    const int b  = blockIdx.z;
    const int t  = threadIdx.x;
    const int tc = t & 15, tr = t >> 4;
    const float* xb = X + (size_t)(b * SEQ + s0) * DMODEL + h * 64;
    const float* mk = Mk + (size_t)h * 64 * 64;
#pragma unroll
    for (int i = 0; i < 4; ++i) {
        int e4  = t + i * 256;
        int row = e4 >> 4;            // 0..63 (s-row for Qs, d-row for Ms)
        int c4  = (e4 & 15) << 2;
        float4 q4 = *(const float4*)(xb + (size_t)row * DMODEL + c4);
        Qs[c4 + 0][row] = q4.x;
        Qs[c4 + 1][row] = q4.y;
        Qs[c4 + 2][row] = q4.z;
        Qs[c4 + 3][row] = q4.w;
        float4 m4 = *(const float4*)(mk + row * 64 + c4);
        *(float4*)&Ms[row][c4] = m4;
    }
    __syncthreads();
    float acc[4][4] = {};
#pragma unroll 16
    for (int kk = 0; kk < 64; ++kk) {
        float a0 = Qs[kk][tr * 4 + 0];
        float a1 = Qs[kk][tr * 4 + 1];
        float a2 = Qs[kk][tr * 4 + 2];
        float a3 = Qs[kk][tr * 4 + 3];
        float4 b4 = *(const float4*)&Ms[kk][tc * 4];
        acc[0][0] += a0 * b4.x; acc[0][1] += a0 * b4.y; acc[0][2] += a0 * b4.z; acc[0][3] += a0 * b4.w;
        acc[1][0] += a1 * b4.x; acc[1][1] += a1 * b4.y; acc[1][2] += a1 * b4.z; acc[1][3] += a1 * b4.w;
        acc[2][0] += a2 * b4.x; acc[2][1] += a2 * b4.y; acc[2][2] += a2 * b4.z; acc[2][3] += a2 * b4.w;
        acc[3][0] += a3 * b4.x; acc[3][1] += a3 * b4.y; acc[3][2] += a3 * b4.z; acc[3][3] += a3 * b4.w;
    }
    float* op = out + ((size_t)(b * NH + h) * SEQ + s0) * 64;
#pragma unroll
    for (int i = 0; i < 4; ++i) {
        float4 o = make_float4(acc[i][0], acc[i][1], acc[i][2], acc[i][3]);
        *(float4*)(op + (size_t)(tr * 4 + i) * 64 + tc * 4) = o;
    }
}

// ------------- flash attention: out[b,s,h*64+c] = softmax(qm@km^T/8) @ vh -------------
// block: 64 q-rows of one (b,h). 256 threads: thread t -> row r=t&63, col-chunk g=t>>6 (16 cols).
__global__ __launch_bounds__(256)
void attn_kernel(const float* __restrict__ QM, const float* __restrict__ KM,
                 const float* __restrict__ V, float* __restrict__ out) {
    __shared__ float qT[64][65];     // [m][r]
    __shared__ float kT[64][68];     // [m][j]  (float4-readable rows)
    __shared__ float vs[64][68];     // [j][c]
    __shared__ float pT[64][65];     // [j][r]
    __shared__ float redmax[64][4];
    __shared__ float redsum[64][4];
    const int s0 = blockIdx.x * 64;
    const int h  = blockIdx.y;
    const int b  = blockIdx.z;
    const int t  = threadIdx.x;
    const int r  = t & 63;
    const int g  = t >> 6;
    const int gb = g * 16;
    const float* qb  = QM + ((size_t)(b * NH + h) * SEQ + s0) * 64;
    const float* kb0 = KM + ((size_t)(b * NH + h) * SEQ) * 64;
    const float* vb0 = V + (size_t)(b * SEQ) * DMODEL + h * 64;

#pragma unroll
    for (int i = 0; i < 4; ++i) {
        int e4  = t + i * 256;
        int row = e4 >> 4;
        int c4  = (e4 & 15) << 2;
        float4 q4 = *(const float4*)(qb + (size_t)row * 64 + c4);
        qT[c4 + 0][row] = q4.x;
        qT[c4 + 1][row] = q4.y;
        qT[c4 + 2][row] = q4.z;
        qT[c4 + 3][row] = q4.w;
    }
    float m_r = -INFINITY, l_r = 0.f;
    float ctx[16];
#pragma unroll
    for (int cc = 0; cc < 16; ++cc) ctx[cc] = 0.f;

    for (int t0 = 0; t0 < SEQ; t0 += 64) {
        __syncthreads();   // BAR1: prev iter's kT/vs/pT reads done
#pragma unroll
        for (int i = 0; i < 4; ++i) {
            int e4  = t + i * 256;
            int row = e4 >> 4;
            int c4  = (e4 & 15) << 2;
            float4 k4 = *(const float4*)(kb0 + (size_t)(t0 + row) * 64 + c4);
            kT[c4 + 0][row] = k4.x;
            kT[c4 + 1][row] = k4.y;
            kT[c4 + 2][row] = k4.z;
            kT[c4 + 3][row] = k4.w;
            float4 v4 = *(const float4*)(vb0 + (size_t)(t0 + row) * DMODEL + c4);
            *(float4*)&vs[row][c4] = v4;
        }
        __syncthreads();   // BAR2: tiles loaded
        float s[16];
#pragma unroll
        for (int jj = 0; jj < 16; ++jj) s[jj] = 0.f;
#pragma unroll 16
        for (int kk = 0; kk < 64; ++kk) {
            float qv = qT[kk][r];
            float4 ka = *(const float4*)&kT[kk][gb + 0];
            float4 kb = *(const float4*)&kT[kk][gb + 4];
            float4 kc = *(const float4*)&kT[kk][gb + 8];
            float4 kd = *(const float4*)&kT[kk][gb + 12];
            s[0]  += qv * ka.x; s[1]  += qv * ka.y; s[2]  += qv * ka.z; s[3]  += qv * ka.w;
            s[4]  += qv * kb.x; s[5]  += qv * kb.y; s[6]  += qv * kb.z; s[7]  += qv * kb.w;
            s[8]  += qv * kc.x; s[9]  += qv * kc.y; s[10] += qv * kc.z; s[11] += qv * kc.w;
            s[12] += qv * kd.x; s[13] += qv * kd.y; s[14] += qv * kd.z; s[15] += qv * kd.w;
        }
        float pm = -INFINITY;
#pragma unroll
        for (int jj = 0; jj < 16; ++jj) { s[jj] *= 0.125f; pm = fmaxf(pm, s[jj]); }
        redmax[r][g] = pm;
        __syncthreads();   // BAR3
        float tm   = fmaxf(fmaxf(redmax[r][0], redmax[r][1]), fmaxf(redmax[r][2], redmax[r][3]));
        float mnew = fmaxf(m_r, tm);
        float alpha = __expf(m_r - mnew);
        float psum = 0.f;
#pragma unroll
        for (int jj = 0; jj < 16; ++jj) { float p = __expf(s[jj] - mnew); s[jj] = p; psum += p; }
        redsum[r][g] = psum;
#pragma unroll
        for (int jj = 0; jj < 16; ++jj) pT[gb + jj][r] = s[jj];
        __syncthreads();   // BAR4
        l_r = l_r * alpha + redsum[r][0] + redsum[r][1] + redsum[r][2] + redsum[r][3];
        m_r = mnew;
#pragma unroll
        for (int cc = 0; cc < 16; ++cc) ctx[cc] *= alpha;
#pragma unroll 8
        for (int j = 0; j < 64; ++j) {
            float pv = pT[j][r];
            float4 va = *(const float4*)&vs[j][gb + 0];
            float4 vb = *(const float4*)&vs[j][gb + 4];
            float4 vc = *(const float4*)&vs[j][gb + 8];
            float4 vd = *(const float4*)&vs[j][gb + 12];
            ctx[0]  += pv * va.x; ctx[1]  += pv * va.y; ctx[2]  += pv * va.z; ctx[3]  += pv * va.w;
            ctx[4]  += pv * vb.x; ctx[5]  += pv * vb.y; ctx[6]  += pv * vb.z; ctx[7]  += pv * vb.w;
            ctx[8]  += pv * vc.x; ctx[9]  += pv * vc.y; ctx[10] += pv * vc.z; ctx[11] += pv * vc.w;
            ctx[12] += pv * vd.x; ctx[13] += pv * vd.y; ctx[14] += pv * vd.z; ctx[15] += pv * vd.w;
        }
    }
    float inv = 1.0f / l_r;
    float* ob = out + ((size_t)(b * SEQ) + s0 + r) * DMODEL + h * 64 + gb;
#pragma unroll
    for (int c4 = 0; c4 < 16; c4 += 4) {
        float4 o = make_float4(ctx[c4] * inv, ctx[c4 + 1] * inv, ctx[c4 + 2] * inv, ctx[c4 + 3] * inv);
        *(float4*)(ob + c4) = o;
    }
}

// ------------- fused residual + LayerNorm: out[i,:] = LN(X[i,:]+R[i,:])*g + b -------------
__global__ __launch_bounds__(256)
void ln_kernel(const float* __restrict__ X, const float* __restrict__ R,
               const float* __restrict__ gw, const float* __restrict__ bw,
               float* __restrict__ out) {
    __shared__ float red[8];
    const int i = blockIdx.x;
    const int t = threadIdx.x;
    const float* xp = X + (size_t)i * DMODEL;
    const float* rp = R + (size_t)i * DMODEL;
    float4 xv = *(const float4*)(xp + t * 4);
    float4 rv = *(const float4*)(rp + t * 4);
    float v0 = xv.x + rv.x, v1 = xv.y + rv.y, v2 = xv.z + rv.z, v3 = xv.w + rv.w;
    float sum = v0 + v1 + v2 + v3;
    float sq  = v0 * v0 + v1 * v1 + v2 * v2 + v3 * v3;
#pragma unroll
    for (int off = 32; off > 0; off >>= 1) {
        sum += __shfl_down(sum, off, 64);
        sq  += __shfl_down(sq,  off, 64);
    }
    int wid = t >> 6;
    if ((t & 63) == 0) { red[wid] = sum; red[4 + wid] = sq; }
    __syncthreads();
    sum = red[0] + red[1] + red[2] + red[3];
    sq  = red[4] + red[5] + red[6] + red[7];
    float mu   = sum * (1.0f / DMODEL);
    float var  = sq * (1.0f / DMODEL) - mu * mu;
    float rstd = rsqrtf(var + 1e-5f);
    float4 gv = *(const float4*)(gw + t * 4);
    float4 bv = *(const float4*)(bw + t * 4);
    float4 o;
    o.x = (v0 - mu) * rstd * gv.x + bv.x;
    o.y = (v1 - mu) * rstd * gv.y + bv.y;
    o.z = (v2 - mu) * rstd * gv.z + bv.z;
    o.w = (v3 - mu) * rstd * gv.w + bv.w;
    *(float4*)(out + (size_t)i * DMODEL + t * 4) = o;
}

extern "C" void kernel_launch(void* const* d_in, const int* in_sizes, int n_in,
                              void* d_out, int out_size, void* d_ws, size_t ws_size,
                              hipStream_t stream) {
    const float* x   = (const float*)d_in[0];
    const float* Wq  = (const float*)d_in[1];
    const float* Wk  = (const float*)d_in[2];
    const float* Wv  = (const float*)d_in[3];
    const float* Wo  = (const float*)d_in[4];
    const float* Mk  = (const float*)d_in[5];
    const float* g1  = (const float*)d_in[6];
    const float* bl1 = (const float*)d_in[7];
    const float* g2  = (const float*)d_in[8];
    const float* bl2 = (const float*)d_in[9];
    const float* W1  = (const float*)d_in[10];
    const float* bf1 = (const float*)d_in[11];
    const float* W2  = (const float*)d_in[12];
    const float* bf2 = (const float*)d_in[13];
    float* out = (float*)d_out;
    float* ws  = (float*)d_ws;

    const size_t U = (size_t)NROWS * DMODEL;  // 4,194,304 floats = 16 MB
    // layout (7 units = 117.4 MB):
    //   u0 q / wo_out / h1[0]   u1 k / h1[1]   u2 v / h1[2]   u3 qm / h1[3]
    //   u4 km / ff2             u5 ctx         u6 y
    float* q      = ws + 0 * U;
    float* k      = ws + 1 * U;
    float* v      = ws + 2 * U;
    float* qm     = ws + 3 * U;
    float* km     = ws + 4 * U;
    float* ctx    = ws + 5 * U;
    float* y      = ws + 6 * U;
    float* wo_out = ws + 0 * U;   // q dead after headproj
    float* h1     = ws + 0 * U;   // spans u0..u3 (q,k,v,qm dead)
    float* ff2    = ws + 4 * U;   // km dead after attention

    dim3 blk(256);
    dim3 gemmDD(DMODEL / 64, NROWS / 64);
    dim3 gemmDF(FDIM / 64, NROWS / 64);
    dim3 hgrid(SEQ / 64, NH, BATCH);

    gemm_kernel<0><<<gemmDD, blk, 0, stream>>>(x, Wq, nullptr, q, DMODEL, DMODEL);
    gemm_kernel<0><<<gemmDD, blk, 0, stream>>>(x, Wk, nullptr, k, DMODEL, DMODEL);
    gemm_kernel<0><<<gemmDD, blk, 0, stream>>>(x, Wv, nullptr, v, DMODEL, DMODEL);
    headproj_kernel<<<hgrid, blk, 0, stream>>>(q, Mk, qm);
    headproj_kernel<<<hgrid, blk, 0, stream>>>(k, Mk, km);
    attn_kernel<<<hgrid, blk, 0, stream>>>(qm, km, v, ctx);
    gemm_kernel<0><<<gemmDD, blk, 0, stream>>>(ctx, Wo, nullptr, wo_out, DMODEL, DMODEL);
    ln_kernel<<<dim3(NROWS), blk, 0, stream>>>(x, wo_out, g1, bl1, y);
    gemm_kernel<1><<<gemmDF, blk, 0, stream>>>(y, W1, bf1, h1, DMODEL, FDIM);
    gemm_kernel<0><<<gemmDD, blk, 0, stream>>>(h1, W2, bf2, ff2, FDIM, DMODEL);
    ln_kernel<<<dim3(NROWS), blk, 0, stream>>>(y, ff2, g2, bl2, out);
}

// Round 7
// 1677.741 us; speedup vs baseline: 1.6609x; 1.6609x over previous
//
#include <hip/hip_runtime.h>
#include <math.h>

#define NH 16
#define DH 64
#define MDIM 64
#define DMODEL 1024
#define FDIM 4096
#define BATCH 2
#define SEQ 2048
#define NROWS (BATCH*SEQ)   // 4096

typedef short bf16x8 __attribute__((ext_vector_type(8)));
typedef float f32x4 __attribute__((ext_vector_type(4)));

__device__ __forceinline__ float gelu_f(float v) {
    return 0.5f * v * (1.0f + erff(v * 0.70710678118654752f));
}
__device__ __forceinline__ ushort f2bf(float f) {
    union { float f; unsigned u; } v; v.f = f;
    unsigned r = v.u + 0x7fffu + ((v.u >> 16) & 1u);
    return (ushort)(r >> 16);
}
__device__ __forceinline__ float bf2f(ushort h) {
    union { unsigned u; float f; } v; v.u = ((unsigned)h) << 16;
    return v.f;
}
__device__ __forceinline__ void gl_lds16(const ushort* g, ushort* l) {
    __builtin_amdgcn_global_load_lds((const __attribute__((address_space(1))) void*)g,
                                     (__attribute__((address_space(3))) void*)l, 16, 0, 0);
}

// ---------------- split (no transpose): fp32 -> hi/lo bf16 planes ----------------
__global__ __launch_bounds__(256)
void splitA_kernel(const float* __restrict__ X, ushort* __restrict__ hi,
                   ushort* __restrict__ lo, int n4) {
    int i = blockIdx.x * 256 + threadIdx.x;
    if (i >= n4) return;
    float4 v = ((const float4*)X)[i];
    ushort4 h, l;
    h.x = f2bf(v.x); l.x = f2bf(v.x - bf2f(h.x));
    h.y = f2bf(v.y); l.y = f2bf(v.y - bf2f(h.y));
    h.z = f2bf(v.z); l.z = f2bf(v.z - bf2f(h.z));
    h.w = f2bf(v.w); l.w = f2bf(v.w - bf2f(h.w));
    ((ushort4*)hi)[i] = h;
    ((ushort4*)lo)[i] = l;
}

// ---------------- split + transpose: W (K x N fp32) -> WT hi/lo (N x K bf16) ----------------
__global__ __launch_bounds__(256)
void splitT_kernel(const float* __restrict__ W, ushort* __restrict__ Thi,
                   ushort* __restrict__ Tlo, int K, int N) {
    __shared__ float tile[64][65];
    const int n0 = blockIdx.x * 64;
    const int k0 = blockIdx.y * 64;
    const int t  = threadIdx.x;
    const int r  = t >> 4;            // 0..15
    const int c4 = (t & 15) * 4;
#pragma unroll
    for (int i = 0; i < 4; ++i) {
        int row = r + i * 16;         // k_local
        float4 v = *(const float4*)&W[(size_t)(k0 + row) * N + n0 + c4];
        tile[c4 + 0][row] = v.x;
        tile[c4 + 1][row] = v.y;
        tile[c4 + 2][row] = v.z;
        tile[c4 + 3][row] = v.w;
    }
    __syncthreads();
#pragma unroll
    for (int i = 0; i < 4; ++i) {
        int row = r + i * 16;         // n_local
        float a = tile[row][c4 + 0], b = tile[row][c4 + 1];
        float c = tile[row][c4 + 2], d = tile[row][c4 + 3];
        ushort4 h, l;
        h.x = f2bf(a); l.x = f2bf(a - bf2f(h.x));
        h.y = f2bf(b); l.y = f2bf(b - bf2f(h.y));
        h.z = f2bf(c); l.z = f2bf(c - bf2f(h.z));
        h.w = f2bf(d); l.w = f2bf(d - bf2f(h.w));
        size_t off = (size_t)(n0 + row) * K + k0 + c4;
        *(ushort4*)&Thi[off] = h;
        *(ushort4*)&Tlo[off] = l;
    }
}

// ---------------- bf16x3 MFMA GEMM ----------------
// C(4096 x N) = A(4096 x K) @ B(K x N), A given as hi/lo bf16 planes (row-major),
// B given as transposed hi/lo bf16 planes BT (N x K row-major).
// 3 K-segments: hi*hi + lo*hi + hi*lo accumulated in fp32.
// tile 128x128, BK=32, 256 threads = 4 waves (2x2), mfma_f32_16x16x32_bf16.
template<int ACT, int SPLIT_OUT>
__global__ __launch_bounds__(256)
void mfma_gemm(const ushort* __restrict__ Ahi, const ushort* __restrict__ Alo,
               const ushort* __restrict__ BThi, const ushort* __restrict__ BTlo,
               const float* __restrict__ bias, float* __restrict__ C,
               ushort* __restrict__ Chi, ushort* __restrict__ Clo,
               int K, int N) {
    __shared__ ushort As[128 * 32];
    __shared__ ushort Bs[128 * 32];
    const int t    = threadIdx.x;
    const int lane = t & 63;
    const int wid  = t >> 6;
    const int wr   = wid >> 1;
    const int wc   = wid & 1;
    const int i0   = blockIdx.y * 128;
    const int n0   = blockIdx.x * 128;
    const int srow = t >> 2;           // staging row within 64-row pass
    const int scol = (t & 3) * 8;      // staging bf16 col
    ushort* aDst0 = As + t * 8;
    ushort* aDst1 = As + 2048 + t * 8;
    ushort* bDst0 = Bs + t * 8;
    ushort* bDst1 = Bs + 2048 + t * 8;

    f32x4 acc[4][4];
#pragma unroll
    for (int m = 0; m < 4; ++m)
#pragma unroll
        for (int n = 0; n < 4; ++n) {
            acc[m][n][0] = 0.f; acc[m][n][1] = 0.f;
            acc[m][n][2] = 0.f; acc[m][n][3] = 0.f;
        }

    const int aOff = (wr * 64 + (lane & 15)) * 32 + (lane >> 4) * 8;
    const int bOff = (wc * 64 + (lane & 15)) * 32 + (lane >> 4) * 8;

    for (int seg = 0; seg < 3; ++seg) {
        const ushort* Ab = (seg == 1) ? Alo : Ahi;
        const ushort* Bb = (seg == 2) ? BTlo : BThi;
        const ushort* Ap0 = Ab + (size_t)(i0 + srow) * K + scol;
        const ushort* Ap1 = Ap0 + (size_t)64 * K;
        const ushort* Bp0 = Bb + (size_t)(n0 + srow) * K + scol;
        const ushort* Bp1 = Bp0 + (size_t)64 * K;
        for (int k0 = 0; k0 < K; k0 += 32) {
            __syncthreads();                 // previous iter's LDS reads done
            gl_lds16(Ap0 + k0, aDst0);
            gl_lds16(Ap1 + k0, aDst1);
            gl_lds16(Bp0 + k0, bDst0);
            gl_lds16(Bp1 + k0, bDst1);
            __syncthreads();                 // loads visible (vmcnt drained)
            bf16x8 af[4], bfr[4];
#pragma unroll
            for (int m = 0; m < 4; ++m)
                af[m] = *(const bf16x8*)&As[aOff + m * 16 * 32];
#pragma unroll
            for (int n = 0; n < 4; ++n)
                bfr[n] = *(const bf16x8*)&Bs[bOff + n * 16 * 32];
#pragma unroll
            for (int m = 0; m < 4; ++m)
#pragma unroll
                for (int n = 0; n < 4; ++n)
                    acc[m][n] = __builtin_amdgcn_mfma_f32_16x16x32_bf16(af[m], bfr[n], acc[m][n], 0, 0, 0);
        }
    }

    // epilogue: C/D layout col=lane&15, row=(lane>>4)*4+r
    const int orow  = i0 + wr * 64 + (lane >> 4) * 4;
    const int ocol0 = n0 + wc * 64 + (lane & 15);
#pragma unroll
    for (int n = 0; n < 4; ++n) {
        const int colg = ocol0 + n * 16;
        float bv = bias ? bias[colg] : 0.f;
#pragma unroll
        for (int m = 0; m < 4; ++m) {
#pragma unroll
            for (int r = 0; r < 4; ++r) {
                const int rowg = orow + m * 16 + r;
                float v = acc[m][n][r] + bv;
                if (ACT == 1) v = gelu_f(v);
                size_t off = (size_t)rowg * N + colg;
                if (SPLIT_OUT) {
                    ushort h = f2bf(v);
                    Chi[off] = h;
                    Clo[off] = f2bf(v - bf2f(h));
                } else {
                    C[off] = v;
                }
            }
        }
    }
}

// ------------- per-head projection: out[b,h,s,m] = sum_d X[b,s,h*64+d]*Mk[h,d,m] -------------
__global__ __launch_bounds__(256)
void headproj_kernel(const float* __restrict__ X, int xstride, const float* __restrict__ Mk,
                     float* __restrict__ out) {
    __shared__ float Qs[64][65];
    __shared__ float Ms[64][68];
    const int s0 = blockIdx.x * 64;
    const int h  = blockIdx.y;
    const int b  = blockIdx.z;
    const int t  = threadIdx.x;
    const int tc = t & 15, tr = t >> 4;
    const float* xb = X + (size_t)(b * SEQ + s0) * xstride + h * 64;
    const float* mk = Mk + (size_t)h * 64 * 64;
#pragma unroll
    for (int i = 0; i < 4; ++i) {
        int e4  = t + i * 256;
        int row = e4 >> 4;
        int c4  = (e4 & 15) << 2;
        float4 q4 = *(const float4*)(xb + (size_t)row * xstride + c4);
        Qs[c4 + 0][row] = q4.x;
        Qs[c4 + 1][row] = q4.y;
        Qs[c4 + 2][row] = q4.z;
        Qs[c4 + 3][row] = q4.w;
        float4 m4 = *(const float4*)(mk + row * 64 + c4);
        *(float4*)&Ms[row][c4] = m4;
    }
    __syncthreads();
    float acc[4][4] = {};
#pragma unroll 16
    for (int kk = 0; kk < 64; ++kk) {
        float a0 = Qs[kk][tr * 4 + 0];
        float a1 = Qs[kk][tr * 4 + 1];
        float a2 = Qs[kk][tr * 4 + 2];
        float a3 = Qs[kk][tr * 4 + 3];
        float4 b4 = *(const float4*)&Ms[kk][tc * 4];
        acc[0][0] += a0 * b4.x; acc[0][1] += a0 * b4.y; acc[0][2] += a0 * b4.z; acc[0][3] += a0 * b4.w;
        acc[1][0] += a1 * b4.x; acc[1][1] += a1 * b4.y; acc[1][2] += a1 * b4.z; acc[1][3] += a1 * b4.w;
        acc[2][0] += a2 * b4.x; acc[2][1] += a2 * b4.y; acc[2][2] += a2 * b4.z; acc[2][3] += a2 * b4.w;
        acc[3][0] += a3 * b4.x; acc[3][1] += a3 * b4.y; acc[3][2] += a3 * b4.z; acc[3][3] += a3 * b4.w;
    }
    float* op = out + ((size_t)(b * NH + h) * SEQ + s0) * 64;
#pragma unroll
    for (int i = 0; i < 4; ++i) {
        float4 o = make_float4(acc[i][0], acc[i][1], acc[i][2], acc[i][3]);
        *(float4*)(op + (size_t)(tr * 4 + i) * 64 + tc * 4) = o;
    }
}

// ------------- flash attention (fp32; V has stride param) -------------
__global__ __launch_bounds__(256)
void attn_kernel(const float* __restrict__ QM, const float* __restrict__ KM,
                 const float* __restrict__ V, int vstride, float* __restrict__ out) {
    __shared__ float qT[64][65];
    __shared__ float kT[64][68];
    __shared__ float vs[64][68];
    __shared__ float pT[64][65];
    __shared__ float redmax[64][4];
    __shared__ float redsum[64][4];
    const int s0 = blockIdx.x * 64;
    const int h  = blockIdx.y;
    const int b  = blockIdx.z;
    const int t  = threadIdx.x;
    const int r  = t & 63;
    const int g  = t >> 6;
    const int gb = g * 16;
    const float* qb  = QM + ((size_t)(b * NH + h) * SEQ + s0) * 64;
    const float* kb0 = KM + ((size_t)(b * NH + h) * SEQ) * 64;
    const float* vb0 = V + (size_t)(b * SEQ) * vstride + h * 64;

#pragma unroll
    for (int i = 0; i < 4; ++i) {
        int e4  = t + i * 256;
        int row = e4 >> 4;
        int c4  = (e4 & 15) << 2;
        float4 q4 = *(const float4*)(qb + (size_t)row * 64 + c4);
        qT[c4 + 0][row] = q4.x;
        qT[c4 + 1][row] = q4.y;
        qT[c4 + 2][row] = q4.z;
        qT[c4 + 3][row] = q4.w;
    }
    float m_r = -INFINITY, l_r = 0.f;
    float ctx[16];
#pragma unroll
    for (int cc = 0; cc < 16; ++cc) ctx[cc] = 0.f;

    for (int t0 = 0; t0 < SEQ; t0 += 64) {
        __syncthreads();
#pragma unroll
        for (int i = 0; i < 4; ++i) {
            int e4  = t + i * 256;
            int row = e4 >> 4;
            int c4  = (e4 & 15) << 2;
            float4 k4 = *(const float4*)(kb0 + (size_t)(t0 + row) * 64 + c4);
            kT[c4 + 0][row] = k4.x;
            kT[c4 + 1][row] = k4.y;
            kT[c4 + 2][row] = k4.z;
            kT[c4 + 3][row] = k4.w;
            float4 v4 = *(const float4*)(vb0 + (size_t)(t0 + row) * vstride + c4);
            *(float4*)&vs[row][c4] = v4;
        }
        __syncthreads();
        float s[16];
#pragma unroll
        for (int jj = 0; jj < 16; ++jj) s[jj] = 0.f;
#pragma unroll 16
        for (int kk = 0; kk < 64; ++kk) {
            float qv = qT[kk][r];
            float4 ka = *(const float4*)&kT[kk][gb + 0];
            float4 kb = *(const float4*)&kT[kk][gb + 4];
            float4 kc = *(const float4*)&kT[kk][gb + 8];
            float4 kd = *(const float4*)&kT[kk][gb + 12];
            s[0]  += qv * ka.x; s[1]  += qv * ka.y; s[2]  += qv * ka.z; s[3]  += qv * ka.w;
            s[4]  += qv * kb.x; s[5]  += qv * kb.y; s[6]  += qv * kb.z; s[7]  += qv * kb.w;
            s[8]  += qv * kc.x; s[9]  += qv * kc.y; s[10] += qv * kc.z; s[11] += qv * kc.w;
            s[12] += qv * kd.x; s[13] += qv * kd.y; s[14] += qv * kd.z; s[15] += qv * kd.w;
        }
        float pm = -INFINITY;
#pragma unroll
        for (int jj = 0; jj < 16; ++jj) { s[jj] *= 0.125f; pm = fmaxf(pm, s[jj]); }
        redmax[r][g] = pm;
        __syncthreads();
        float tm   = fmaxf(fmaxf(redmax[r][0], redmax[r][1]), fmaxf(redmax[r][2], redmax[r][3]));
        float mnew = fmaxf(m_r, tm);
        float alpha = __expf(m_r - mnew);
        float psum = 0.f;
#pragma unroll
        for (int jj = 0; jj < 16; ++jj) { float p = __expf(s[jj] - mnew); s[jj] = p; psum += p; }
        redsum[r][g] = psum;
#pragma unroll
        for (int jj = 0; jj < 16; ++jj) pT[gb + jj][r] = s[jj];
        __syncthreads();
        l_r = l_r * alpha + redsum[r][0] + redsum[r][1] + redsum[r][2] + redsum[r][3];
        m_r = mnew;
#pragma unroll
        for (int cc = 0; cc < 16; ++cc) ctx[cc] *= alpha;
#pragma unroll 8
        for (int j = 0; j < 64; ++j) {
            float pv = pT[j][r];
            float4 va = *(const float4*)&vs[j][gb + 0];
            float4 vb = *(const float4*)&vs[j][gb + 4];
            float4 vc = *(const float4*)&vs[j][gb + 8];
            float4 vd = *(const float4*)&vs[j][gb + 12];
            ctx[0]  += pv * va.x; ctx[1]  += pv * va.y; ctx[2]  += pv * va.z; ctx[3]  += pv * va.w;
            ctx[4]  += pv * vb.x; ctx[5]  += pv * vb.y; ctx[6]  += pv * vb.z; ctx[7]  += pv * vb.w;
            ctx[8]  += pv * vc.x; ctx[9]  += pv * vc.y; ctx[10] += pv * vc.z; ctx[11] += pv * vc.w;
            ctx[12] += pv * vd.x; ctx[13] += pv * vd.y; ctx[14] += pv * vd.z; ctx[15] += pv * vd.w;
        }
    }
    float inv = 1.0f / l_r;
    float* ob = out + ((size_t)(b * SEQ) + s0 + r) * DMODEL + h * 64 + gb;
#pragma unroll
    for (int c4 = 0; c4 < 16; c4 += 4) {
        float4 o = make_float4(ctx[c4] * inv, ctx[c4 + 1] * inv, ctx[c4 + 2] * inv, ctx[c4 + 3] * inv);
        *(float4*)(ob + c4) = o;
    }
}

// ------------- fused residual + LayerNorm (+ optional bf16 hi/lo split of output) -------------
__global__ __launch_bounds__(256)
void ln_kernel(const float* __restrict__ X, const float* __restrict__ R,
               const float* __restrict__ gw, const float* __restrict__ bw,
               float* __restrict__ out, ushort* __restrict__ ohi, ushort* __restrict__ olo) {
    __shared__ float red[8];
    const int i = blockIdx.x;
    const int t = threadIdx.x;
    const float* xp = X + (size_t)i * DMODEL;
    const float* rp = R + (size_t)i * DMODEL;
    float4 xv = *(const float4*)(xp + t * 4);
    float4 rv = *(const float4*)(rp + t * 4);
    float v0 = xv.x + rv.x, v1 = xv.y + rv.y, v2 = xv.z + rv.z, v3 = xv.w + rv.w;
    float sum = v0 + v1 + v2 + v3;
    float sq  = v0 * v0 + v1 * v1 + v2 * v2 + v3 * v3;
#pragma unroll
    for (int off = 32; off > 0; off >>= 1) {
        sum += __shfl_down(sum, off, 64);
        sq  += __shfl_down(sq,  off, 64);
    }
    int wid = t >> 6;
    if ((t & 63) == 0) { red[wid] = sum; red[4 + wid] = sq; }
    __syncthreads();
    sum = red[0] + red[1] + red[2] + red[3];
    sq  = red[4] + red[5] + red[6] + red[7];
    float mu   = sum * (1.0f / DMODEL);
    float var  = sq * (1.0f / DMODEL) - mu * mu;
    float rstd = rsqrtf(var + 1e-5f);
    float4 gv = *(const float4*)(gw + t * 4);
    float4 bv = *(const float4*)(bw + t * 4);
    float4 o;
    o.x = (v0 - mu) * rstd * gv.x + bv.x;
    o.y = (v1 - mu) * rstd * gv.y + bv.y;
    o.z = (v2 - mu) * rstd * gv.z + bv.z;
    o.w = (v3 - mu) * rstd * gv.w + bv.w;
    *(float4*)(out + (size_t)i * DMODEL + t * 4) = o;
    if (ohi) {
        ushort4 h, l;
        h.x = f2bf(o.x); l.x = f2bf(o.x - bf2f(h.x));
        h.y = f2bf(o.y); l.y = f2bf(o.y - bf2f(h.y));
        h.z = f2bf(o.z); l.z = f2bf(o.z - bf2f(h.z));
        h.w = f2bf(o.w); l.w = f2bf(o.w - bf2f(h.w));
        size_t off = (size_t)i * DMODEL + t * 4;
        *(ushort4*)&ohi[off] = h;
        *(ushort4*)&olo[off] = l;
    }
}

extern "C" void kernel_launch(void* const* d_in, const int* in_sizes, int n_in,
                              void* d_out, int out_size, void* d_ws, size_t ws_size,
                              hipStream_t stream) {
    const float* x   = (const float*)d_in[0];
    const float* Wq  = (const float*)d_in[1];
    const float* Wk  = (const float*)d_in[2];
    const float* Wv  = (const float*)d_in[3];
    const float* Wo  = (const float*)d_in[4];
    const float* Mk  = (const float*)d_in[5];
    const float* g1  = (const float*)d_in[6];
    const float* bl1 = (const float*)d_in[7];
    const float* g2  = (const float*)d_in[8];
    const float* bl2 = (const float*)d_in[9];
    const float* W1  = (const float*)d_in[10];
    const float* bf1 = (const float*)d_in[11];
    const float* W2  = (const float*)d_in[12];
    const float* bf2 = (const float*)d_in[13];
    float* out = (float*)d_out;
    char* wsb  = (char*)d_ws;

    const size_t MB = 1024 * 1024;
    // ---- workspace layout, peak 192 MB ----
    // [0,48)    qkv fp32 (4096x3072)          -> dead after attn; h1 planes reuse
    // [48,64)   qm                            -> dead after attn
    // [64,80)   km / wo_out                   -> dead after LN1
    // [80,96)   ctx fp32                      -> dead after ctx split; ff2 reuses
    // [96,112)  y fp32
    // [112,160) weight planes (48 MB)
    // [160,176) x_hi/x_lo -> dead after QKV; ctx_hi/ctx_lo reuse
    // [176,192) y_hi/y_lo
    float* qkv    = (float*)(wsb + 0 * MB);
    float* qm     = (float*)(wsb + 48 * MB);
    float* km     = (float*)(wsb + 64 * MB);
    float* ctx    = (float*)(wsb + 80 * MB);
    float* y      = (float*)(wsb + 96 * MB);
    float* wo_out = km;
    float* ff2    = ctx;
    ushort* wqkvT_hi = (ushort*)(wsb + 112 * MB);   // 3072x1024 = 6 MB
    ushort* wqkvT_lo = (ushort*)(wsb + 118 * MB);
    ushort* woT_hi   = (ushort*)(wsb + 124 * MB);   // 2 MB
    ushort* woT_lo   = (ushort*)(wsb + 126 * MB);
    ushort* w1T_hi   = (ushort*)(wsb + 128 * MB);   // 8 MB
    ushort* w1T_lo   = (ushort*)(wsb + 136 * MB);
    ushort* w2T_hi   = (ushort*)(wsb + 144 * MB);   // 8 MB
    ushort* w2T_lo   = (ushort*)(wsb + 152 * MB);
    ushort* x_hi   = (ushort*)(wsb + 160 * MB);
    ushort* x_lo   = (ushort*)(wsb + 168 * MB);
    ushort* ctx_hi = x_hi;                           // x planes dead after QKV
    ushort* ctx_lo = x_lo;
    ushort* y_hi   = (ushort*)(wsb + 176 * MB);
    ushort* y_lo   = (ushort*)(wsb + 184 * MB);
    ushort* h1_hi  = (ushort*)(wsb + 0 * MB);        // 32 MB, over dead qkv
    ushort* h1_lo  = (ushort*)(wsb + 32 * MB);       // 32 MB, over dead qkv+qm

    dim3 blk(256);
    // --- weight prep (split + transpose) ---
    splitT_kernel<<<dim3(16, 16), blk, 0, stream>>>(Wq, wqkvT_hi, wqkvT_lo, DMODEL, DMODEL);
    splitT_kernel<<<dim3(16, 16), blk, 0, stream>>>(Wk, wqkvT_hi + (size_t)1024 * 1024, wqkvT_lo + (size_t)1024 * 1024, DMODEL, DMODEL);
    splitT_kernel<<<dim3(16, 16), blk, 0, stream>>>(Wv, wqkvT_hi + (size_t)2048 * 1024, wqkvT_lo + (size_t)2048 * 1024, DMODEL, DMODEL);
    splitT_kernel<<<dim3(16, 16), blk, 0, stream>>>(Wo, woT_hi, woT_lo, DMODEL, DMODEL);
    splitT_kernel<<<dim3(64, 16), blk, 0, stream>>>(W1, w1T_hi, w1T_lo, DMODEL, FDIM);
    splitT_kernel<<<dim3(16, 64), blk, 0, stream>>>(W2, w2T_hi, w2T_lo, FDIM, DMODEL);
    // --- x split ---
    splitA_kernel<<<dim3(4096), blk, 0, stream>>>(x, x_hi, x_lo, NROWS * DMODEL / 4);
    // --- fused QKV projection: (4096 x 3072) ---
    mfma_gemm<0, 0><<<dim3(24, 32), blk, 0, stream>>>(x_hi, x_lo, wqkvT_hi, wqkvT_lo,
                                                      nullptr, qkv, nullptr, nullptr, DMODEL, 3072);
    // --- memory-key projections (fp32) ---
    headproj_kernel<<<dim3(32, NH, BATCH), blk, 0, stream>>>(qkv + 0,    3072, Mk, qm);
    headproj_kernel<<<dim3(32, NH, BATCH), blk, 0, stream>>>(qkv + 1024, 3072, Mk, km);
    // --- attention (fp32) ---
    attn_kernel<<<dim3(32, NH, BATCH), blk, 0, stream>>>(qm, km, qkv + 2048, 3072, ctx);
    // --- Wo projection ---
    splitA_kernel<<<dim3(4096), blk, 0, stream>>>(ctx, ctx_hi, ctx_lo, NROWS * DMODEL / 4);
    mfma_gemm<0, 0><<<dim3(8, 32), blk, 0, stream>>>(ctx_hi, ctx_lo, woT_hi, woT_lo,
                                                     nullptr, wo_out, nullptr, nullptr, DMODEL, DMODEL);
    // --- LN1 (+ split of y) ---
    ln_kernel<<<dim3(NROWS), blk, 0, stream>>>(x, wo_out, g1, bl1, y, y_hi, y_lo);
    // --- FFN1: bias + GELU + split fused; no fp32 h1 ---
    mfma_gemm<1, 1><<<dim3(32, 32), blk, 0, stream>>>(y_hi, y_lo, w1T_hi, w1T_lo,
                                                      bf1, nullptr, h1_hi, h1_lo, DMODEL, FDIM);
    // --- FFN2 ---
    mfma_gemm<0, 0><<<dim3(8, 32), blk, 0, stream>>>(h1_hi, h1_lo, w2T_hi, w2T_lo,
                                                     bf2, ff2, nullptr, nullptr, FDIM, DMODEL);
    // --- LN2 -> out ---
    ln_kernel<<<dim3(NROWS), blk, 0, stream>>>(y, ff2, g2, bl2, out, nullptr, nullptr);
}

// Round 8
// 1255.550 us; speedup vs baseline: 2.2193x; 1.3363x over previous
//
#include <hip/hip_runtime.h>
#include <math.h>

#define NH 16
#define DH 64
#define MDIM 64
#define DMODEL 1024
#define FDIM 4096
#define BATCH 2
#define SEQ 2048
#define NROWS (BATCH*SEQ)   // 4096

typedef short bf16x8 __attribute__((ext_vector_type(8)));
typedef float f32x4 __attribute__((ext_vector_type(4)));

__device__ __forceinline__ float gelu_f(float v) {
    return 0.5f * v * (1.0f + erff(v * 0.70710678118654752f));
}
__device__ __forceinline__ ushort f2bf(float f) {
    union { float f; unsigned u; } v; v.f = f;
    unsigned r = v.u + 0x7fffu + ((v.u >> 16) & 1u);
    return (ushort)(r >> 16);
}
__device__ __forceinline__ float bf2f(ushort h) {
    union { unsigned u; float f; } v; v.u = ((unsigned)h) << 16;
    return v.f;
}
__device__ __forceinline__ void gl_lds16(const ushort* g, ushort* l) {
    __builtin_amdgcn_global_load_lds((const __attribute__((address_space(1))) void*)g,
                                     (__attribute__((address_space(3))) void*)l, 16, 0, 0);
}

// ---------------- split (no transpose): fp32 -> hi/lo bf16 planes ----------------
__global__ __launch_bounds__(256)
void splitA_kernel(const float* __restrict__ X, ushort* __restrict__ hi,
                   ushort* __restrict__ lo, int n4) {
    int i = blockIdx.x * 256 + threadIdx.x;
    if (i >= n4) return;
    float4 v = ((const float4*)X)[i];
    ushort4 h, l;
    h.x = f2bf(v.x); l.x = f2bf(v.x - bf2f(h.x));
    h.y = f2bf(v.y); l.y = f2bf(v.y - bf2f(h.y));
    h.z = f2bf(v.z); l.z = f2bf(v.z - bf2f(h.z));
    h.w = f2bf(v.w); l.w = f2bf(v.w - bf2f(h.w));
    ((ushort4*)hi)[i] = h;
    ((ushort4*)lo)[i] = l;
}

// ---------------- split + transpose: W (K x N fp32) -> WT hi/lo (N x K bf16) ----------------
__global__ __launch_bounds__(256)
void splitT_kernel(const float* __restrict__ W, ushort* __restrict__ Thi,
                   ushort* __restrict__ Tlo, int K, int N) {
    __shared__ float tile[64][65];
    const int n0 = blockIdx.x * 64;
    const int k0 = blockIdx.y * 64;
    const int t  = threadIdx.x;
    const int r  = t >> 4;            // 0..15
    const int c4 = (t & 15) * 4;
#pragma unroll
    for (int i = 0; i < 4; ++i) {
        int row = r + i * 16;         // k_local
        float4 v = *(const float4*)&W[(size_t)(k0 + row) * N + n0 + c4];
        tile[c4 + 0][row] = v.x;
        tile[c4 + 1][row] = v.y;
        tile[c4 + 2][row] = v.z;
        tile[c4 + 3][row] = v.w;
    }
    __syncthreads();
#pragma unroll
    for (int i = 0; i < 4; ++i) {
        int row = r + i * 16;         // n_local
        float a = tile[row][c4 + 0], b = tile[row][c4 + 1];
        float c = tile[row][c4 + 2], d = tile[row][c4 + 3];
        ushort4 h, l;
        h.x = f2bf(a); l.x = f2bf(a - bf2f(h.x));
        h.y = f2bf(b); l.y = f2bf(b - bf2f(h.y));
        h.z = f2bf(c); l.z = f2bf(c - bf2f(h.z));
        h.w = f2bf(d); l.w = f2bf(d - bf2f(h.w));
        size_t off = (size_t)(n0 + row) * K + k0 + c4;
        *(ushort4*)&Thi[off] = h;
        *(ushort4*)&Tlo[off] = l;
    }
}

// ---------------- bf16x3 MFMA GEMM (validated Round 7) ----------------
template<int ACT, int SPLIT_OUT>
__global__ __launch_bounds__(256)
void mfma_gemm(const ushort* __restrict__ Ahi, const ushort* __restrict__ Alo,
               const ushort* __restrict__ BThi, const ushort* __restrict__ BTlo,
               const float* __restrict__ bias, float* __restrict__ C,
               ushort* __restrict__ Chi, ushort* __restrict__ Clo,
               int K, int N) {
    __shared__ ushort As[128 * 32];
    __shared__ ushort Bs[128 * 32];
    const int t    = threadIdx.x;
    const int lane = t & 63;
    const int wid  = t >> 6;
    const int wr   = wid >> 1;
    const int wc   = wid & 1;
    const int i0   = blockIdx.y * 128;
    const int n0   = blockIdx.x * 128;
    const int srow = t >> 2;
    const int scol = (t & 3) * 8;
    ushort* aDst0 = As + t * 8;
    ushort* aDst1 = As + 2048 + t * 8;
    ushort* bDst0 = Bs + t * 8;
    ushort* bDst1 = Bs + 2048 + t * 8;

    f32x4 acc[4][4];
#pragma unroll
    for (int m = 0; m < 4; ++m)
#pragma unroll
        for (int n = 0; n < 4; ++n) {
            acc[m][n][0] = 0.f; acc[m][n][1] = 0.f;
            acc[m][n][2] = 0.f; acc[m][n][3] = 0.f;
        }

    const int aOff = (wr * 64 + (lane & 15)) * 32 + (lane >> 4) * 8;
    const int bOff = (wc * 64 + (lane & 15)) * 32 + (lane >> 4) * 8;

    for (int seg = 0; seg < 3; ++seg) {
        const ushort* Ab = (seg == 1) ? Alo : Ahi;
        const ushort* Bb = (seg == 2) ? BTlo : BThi;
        const ushort* Ap0 = Ab + (size_t)(i0 + srow) * K + scol;
        const ushort* Ap1 = Ap0 + (size_t)64 * K;
        const ushort* Bp0 = Bb + (size_t)(n0 + srow) * K + scol;
        const ushort* Bp1 = Bp0 + (size_t)64 * K;
        for (int k0 = 0; k0 < K; k0 += 32) {
            __syncthreads();
            gl_lds16(Ap0 + k0, aDst0);
            gl_lds16(Ap1 + k0, aDst1);
            gl_lds16(Bp0 + k0, bDst0);
            gl_lds16(Bp1 + k0, bDst1);
            __syncthreads();
            bf16x8 af[4], bfr[4];
#pragma unroll
            for (int m = 0; m < 4; ++m)
                af[m] = *(const bf16x8*)&As[aOff + m * 16 * 32];
#pragma unroll
            for (int n = 0; n < 4; ++n)
                bfr[n] = *(const bf16x8*)&Bs[bOff + n * 16 * 32];
#pragma unroll
            for (int m = 0; m < 4; ++m)
#pragma unroll
                for (int n = 0; n < 4; ++n)
                    acc[m][n] = __builtin_amdgcn_mfma_f32_16x16x32_bf16(af[m], bfr[n], acc[m][n], 0, 0, 0);
        }
    }

    const int orow  = i0 + wr * 64 + (lane >> 4) * 4;
    const int ocol0 = n0 + wc * 64 + (lane & 15);
#pragma unroll
    for (int n = 0; n < 4; ++n) {
        const int colg = ocol0 + n * 16;
        float bv = bias ? bias[colg] : 0.f;
#pragma unroll
        for (int m = 0; m < 4; ++m) {
#pragma unroll
            for (int r = 0; r < 4; ++r) {
                const int rowg = orow + m * 16 + r;
                float v = acc[m][n][r] + bv;
                if (ACT == 1) v = gelu_f(v);
                size_t off = (size_t)rowg * N + colg;
                if (SPLIT_OUT) {
                    ushort h = f2bf(v);
                    Chi[off] = h;
                    Clo[off] = f2bf(v - bf2f(h));
                } else {
                    C[off] = v;
                }
            }
        }
    }
}

// ------------- per-head projection -> bf16 hi/lo planes (b,h,s,m) -------------
__global__ __launch_bounds__(256)
void headproj_kernel(const float* __restrict__ X, int xstride, const float* __restrict__ Mk,
                     ushort* __restrict__ oh, ushort* __restrict__ ol) {
    __shared__ float Qs[64][65];
    __shared__ float Ms[64][68];
    const int s0 = blockIdx.x * 64;
    const int h  = blockIdx.y;
    const int b  = blockIdx.z;
    const int t  = threadIdx.x;
    const int tc = t & 15, tr = t >> 4;
    const float* xb = X + (size_t)(b * SEQ + s0) * xstride + h * 64;
    const float* mk = Mk + (size_t)h * 64 * 64;
#pragma unroll
    for (int i = 0; i < 4; ++i) {
        int e4  = t + i * 256;
        int row = e4 >> 4;
        int c4  = (e4 & 15) << 2;
        float4 q4 = *(const float4*)(xb + (size_t)row * xstride + c4);
        Qs[c4 + 0][row] = q4.x;
        Qs[c4 + 1][row] = q4.y;
        Qs[c4 + 2][row] = q4.z;
        Qs[c4 + 3][row] = q4.w;
        float4 m4 = *(const float4*)(mk + row * 64 + c4);
        *(float4*)&Ms[row][c4] = m4;
    }
    __syncthreads();
    float acc[4][4] = {};
#pragma unroll 16
    for (int kk = 0; kk < 64; ++kk) {
        float a0 = Qs[kk][tr * 4 + 0];
        float a1 = Qs[kk][tr * 4 + 1];
        float a2 = Qs[kk][tr * 4 + 2];
        float a3 = Qs[kk][tr * 4 + 3];
        float4 b4 = *(const float4*)&Ms[kk][tc * 4];
        acc[0][0] += a0 * b4.x; acc[0][1] += a0 * b4.y; acc[0][2] += a0 * b4.z; acc[0][3] += a0 * b4.w;
        acc[1][0] += a1 * b4.x; acc[1][1] += a1 * b4.y; acc[1][2] += a1 * b4.z; acc[1][3] += a1 * b4.w;
        acc[2][0] += a2 * b4.x; acc[2][1] += a2 * b4.y; acc[2][2] += a2 * b4.z; acc[2][3] += a2 * b4.w;
        acc[3][0] += a3 * b4.x; acc[3][1] += a3 * b4.y; acc[3][2] += a3 * b4.z; acc[3][3] += a3 * b4.w;
    }
    ushort* oph = oh + ((size_t)(b * NH + h) * SEQ + s0) * 64;
    ushort* opl = ol + ((size_t)(b * NH + h) * SEQ + s0) * 64;
#pragma unroll
    for (int i = 0; i < 4; ++i) {
        ushort4 h4, l4;
        h4.x = f2bf(acc[i][0]); l4.x = f2bf(acc[i][0] - bf2f(h4.x));
        h4.y = f2bf(acc[i][1]); l4.y = f2bf(acc[i][1] - bf2f(h4.y));
        h4.z = f2bf(acc[i][2]); l4.z = f2bf(acc[i][2] - bf2f(h4.z));
        h4.w = f2bf(acc[i][3]); l4.w = f2bf(acc[i][3] - bf2f(h4.w));
        *(ushort4*)(oph + (size_t)(tr * 4 + i) * 64 + tc * 4) = h4;
        *(ushort4*)(opl + (size_t)(tr * 4 + i) * 64 + tc * 4) = l4;
    }
}

// ------------- V slice: split + transpose -> vT hi/lo planes (b,h,d,s) -------------
__global__ __launch_bounds__(256)
void vsplitT_kernel(const float* __restrict__ qkv, ushort* __restrict__ vth,
                    ushort* __restrict__ vtl) {
    __shared__ float tile[64][65];
    const int s0 = blockIdx.x * 64;
    const int h  = blockIdx.y;
    const int b  = blockIdx.z;
    const int t  = threadIdx.x;
    const int r  = t >> 4;
    const int c4 = (t & 15) * 4;
    const float* src = qkv + (size_t)(b * SEQ + s0) * 3072 + 2048 + h * 64;
#pragma unroll
    for (int i = 0; i < 4; ++i) {
        int srow = r + i * 16;
        float4 v = *(const float4*)(src + (size_t)srow * 3072 + c4);
        tile[c4 + 0][srow] = v.x;
        tile[c4 + 1][srow] = v.y;
        tile[c4 + 2][srow] = v.z;
        tile[c4 + 3][srow] = v.w;
    }
    __syncthreads();
    const size_t obase = (size_t)(b * NH + h) * 64 * SEQ + s0;
#pragma unroll
    for (int i = 0; i < 4; ++i) {
        int d = r + i * 16;
        float a = tile[d][c4 + 0], bb = tile[d][c4 + 1];
        float c = tile[d][c4 + 2], dd = tile[d][c4 + 3];
        ushort4 h4, l4;
        h4.x = f2bf(a);  l4.x = f2bf(a - bf2f(h4.x));
        h4.y = f2bf(bb); l4.y = f2bf(bb - bf2f(h4.y));
        h4.z = f2bf(c);  l4.z = f2bf(c - bf2f(h4.z));
        h4.w = f2bf(dd); l4.w = f2bf(dd - bf2f(h4.w));
        *(ushort4*)&vth[obase + (size_t)d * SEQ + c4] = h4;
        *(ushort4*)&vtl[obase + (size_t)d * SEQ + c4] = l4;
    }
}

// ------------- MFMA flash attention, bf16x3 both matmuls -------------
// grid (SEQ/64, NH, BATCH), 4 waves; wave w owns q-rows [q0+16w, q0+16w+16).
// K/V^T fragments read from global (L1/L2-served). P transposed via wave-private
// swizzled LDS (no barriers). ctx written directly as bf16 hi/lo planes.
__global__ __launch_bounds__(256)
void attn_mfma(const ushort* __restrict__ qmh, const ushort* __restrict__ qml,
               const ushort* __restrict__ kmh, const ushort* __restrict__ kml,
               const ushort* __restrict__ vth, const ushort* __restrict__ vtl,
               ushort* __restrict__ ctx_hi, ushort* __restrict__ ctx_lo) {
    __shared__ ushort pbuf[4][2][1024];   // [wave][hi/lo][16q x 64kv], XOR-swizzled
    const int q0 = blockIdx.x * 64;
    const int h  = blockIdx.y;
    const int b  = blockIdx.z;
    const int t  = threadIdx.x;
    const int lane = t & 63;
    const int w  = t >> 6;
    const int rg = lane >> 4;      // 0..3
    const int lc = lane & 15;
    const size_t bh = (size_t)b * NH + h;

    // Q fragments (A): row=lc (q_local), k=m=rg*8 + 32*ks
    const ushort* qb_h = qmh + (bh * SEQ + q0 + w * 16 + lc) * 64 + rg * 8;
    const ushort* qb_l = qml + (bh * SEQ + q0 + w * 16 + lc) * 64 + rg * 8;
    bf16x8 qfh[2], qfl[2];
    qfh[0] = *(const bf16x8*)(qb_h);
    qfh[1] = *(const bf16x8*)(qb_h + 32);
    qfl[0] = *(const bf16x8*)(qb_l);
    qfl[1] = *(const bf16x8*)(qb_l + 32);

    const ushort* kb_h = kmh + (bh * SEQ + lc) * 64 + rg * 8;
    const ushort* kb_l = kml + (bh * SEQ + lc) * 64 + rg * 8;
    const ushort* vb_h = vth + (bh * 64 + lc) * SEQ + rg * 8;
    const ushort* vb_l = vtl + (bh * 64 + lc) * SEQ + rg * 8;

    f32x4 ctx[4];
#pragma unroll
    for (int n = 0; n < 4; ++n) { ctx[n][0] = 0.f; ctx[n][1] = 0.f; ctx[n][2] = 0.f; ctx[n][3] = 0.f; }
    float m_r[4] = { -INFINITY, -INFINITY, -INFINITY, -INFINITY };
    float l_r[4] = { 0.f, 0.f, 0.f, 0.f };

    ushort* ph = &pbuf[w][0][0];
    ushort* pl = &pbuf[w][1][0];

    for (int kv0 = 0; kv0 < SEQ; kv0 += 64) {
        // ---- QK^T (bf16x3): S[q][kv] over this 64-kv window ----
        f32x4 sacc[4];
#pragma unroll
        for (int n = 0; n < 4; ++n) { sacc[n][0] = 0.f; sacc[n][1] = 0.f; sacc[n][2] = 0.f; sacc[n][3] = 0.f; }
        bf16x8 bf[4][2];
#pragma unroll
        for (int n = 0; n < 4; ++n) {
            bf[n][0] = *(const bf16x8*)(kb_h + (size_t)(kv0 + 16 * n) * 64);
            bf[n][1] = *(const bf16x8*)(kb_h + (size_t)(kv0 + 16 * n) * 64 + 32);
        }
#pragma unroll
        for (int n = 0; n < 4; ++n) {
            sacc[n] = __builtin_amdgcn_mfma_f32_16x16x32_bf16(qfh[0], bf[n][0], sacc[n], 0, 0, 0);
            sacc[n] = __builtin_amdgcn_mfma_f32_16x16x32_bf16(qfh[1], bf[n][1], sacc[n], 0, 0, 0);
            sacc[n] = __builtin_amdgcn_mfma_f32_16x16x32_bf16(qfl[0], bf[n][0], sacc[n], 0, 0, 0);
            sacc[n] = __builtin_amdgcn_mfma_f32_16x16x32_bf16(qfl[1], bf[n][1], sacc[n], 0, 0, 0);
        }
#pragma unroll
        for (int n = 0; n < 4; ++n) {
            bf[n][0] = *(const bf16x8*)(kb_l + (size_t)(kv0 + 16 * n) * 64);
            bf[n][1] = *(const bf16x8*)(kb_l + (size_t)(kv0 + 16 * n) * 64 + 32);
        }
#pragma unroll
        for (int n = 0; n < 4; ++n) {
            sacc[n] = __builtin_amdgcn_mfma_f32_16x16x32_bf16(qfh[0], bf[n][0], sacc[n], 0, 0, 0);
            sacc[n] = __builtin_amdgcn_mfma_f32_16x16x32_bf16(qfh[1], bf[n][1], sacc[n], 0, 0, 0);
        }
        // ---- online softmax (per reg r = q row rg*4+r; reduce over 16-lane group) ----
#pragma unroll
        for (int r = 0; r < 4; ++r) {
            float s0 = sacc[0][r] * 0.125f;
            float s1 = sacc[1][r] * 0.125f;
            float s2 = sacc[2][r] * 0.125f;
            float s3 = sacc[3][r] * 0.125f;
            float pm = fmaxf(fmaxf(s0, s1), fmaxf(s2, s3));
            pm = fmaxf(pm, __shfl_xor(pm, 1));
            pm = fmaxf(pm, __shfl_xor(pm, 2));
            pm = fmaxf(pm, __shfl_xor(pm, 4));
            pm = fmaxf(pm, __shfl_xor(pm, 8));
            float mnew  = fmaxf(m_r[r], pm);
            float alpha = __expf(m_r[r] - mnew);
            m_r[r] = mnew;
            float p0 = __expf(s0 - mnew);
            float p1 = __expf(s1 - mnew);
            float p2 = __expf(s2 - mnew);
            float p3 = __expf(s3 - mnew);
            float rs = p0 + p1 + p2 + p3;
            rs += __shfl_xor(rs, 1);
            rs += __shfl_xor(rs, 2);
            rs += __shfl_xor(rs, 4);
            rs += __shfl_xor(rs, 8);
            l_r[r] = l_r[r] * alpha + rs;
            ctx[0][r] *= alpha; ctx[1][r] *= alpha; ctx[2][r] *= alpha; ctx[3][r] *= alpha;
            // P -> bf16 hi/lo into wave-private swizzled LDS [q][kv]
            const int q = rg * 4 + r;
            const int swz = (q & 7) << 3;
            const int rowb = q * 64;
            ushort hh;
            hh = f2bf(p0); ph[(rowb + lc)      ^ swz] = hh; pl[(rowb + lc)      ^ swz] = f2bf(p0 - bf2f(hh));
            hh = f2bf(p1); ph[(rowb + lc + 16) ^ swz] = hh; pl[(rowb + lc + 16) ^ swz] = f2bf(p1 - bf2f(hh));
            hh = f2bf(p2); ph[(rowb + lc + 32) ^ swz] = hh; pl[(rowb + lc + 32) ^ swz] = f2bf(p2 - bf2f(hh));
            hh = f2bf(p3); ph[(rowb + lc + 48) ^ swz] = hh; pl[(rowb + lc + 48) ^ swz] = f2bf(p3 - bf2f(hh));
        }
        // ---- PV (bf16x3): ctx += P @ V ----
        bf16x8 pah[2], pal[2];
        {
            const int swz = (lc & 7) << 3;
            pah[0] = *(const bf16x8*)&ph[(lc * 64 + rg * 8)      ^ swz];
            pah[1] = *(const bf16x8*)&ph[(lc * 64 + rg * 8 + 32) ^ swz];
            pal[0] = *(const bf16x8*)&pl[(lc * 64 + rg * 8)      ^ swz];
            pal[1] = *(const bf16x8*)&pl[(lc * 64 + rg * 8 + 32) ^ swz];
        }
#pragma unroll
        for (int n = 0; n < 4; ++n) {
            bf[n][0] = *(const bf16x8*)(vb_h + (size_t)(16 * n) * SEQ + kv0);
            bf[n][1] = *(const bf16x8*)(vb_h + (size_t)(16 * n) * SEQ + kv0 + 32);
        }
#pragma unroll
        for (int n = 0; n < 4; ++n) {
            ctx[n] = __builtin_amdgcn_mfma_f32_16x16x32_bf16(pah[0], bf[n][0], ctx[n], 0, 0, 0);
            ctx[n] = __builtin_amdgcn_mfma_f32_16x16x32_bf16(pah[1], bf[n][1], ctx[n], 0, 0, 0);
            ctx[n] = __builtin_amdgcn_mfma_f32_16x16x32_bf16(pal[0], bf[n][0], ctx[n], 0, 0, 0);
            ctx[n] = __builtin_amdgcn_mfma_f32_16x16x32_bf16(pal[1], bf[n][1], ctx[n], 0, 0, 0);
        }
#pragma unroll
        for (int n = 0; n < 4; ++n) {
            bf[n][0] = *(const bf16x8*)(vb_l + (size_t)(16 * n) * SEQ + kv0);
            bf[n][1] = *(const bf16x8*)(vb_l + (size_t)(16 * n) * SEQ + kv0 + 32);
        }
#pragma unroll
        for (int n = 0; n < 4; ++n) {
            ctx[n] = __builtin_amdgcn_mfma_f32_16x16x32_bf16(pah[0], bf[n][0], ctx[n], 0, 0, 0);
            ctx[n] = __builtin_amdgcn_mfma_f32_16x16x32_bf16(pah[1], bf[n][1], ctx[n], 0, 0, 0);
        }
    }
    // ---- epilogue: normalize, write ctx hi/lo planes at (b,s,h*64+d) ----
#pragma unroll
    for (int r = 0; r < 4; ++r) {
        float inv = 1.0f / l_r[r];
        const int q = q0 + w * 16 + rg * 4 + r;
        size_t base = ((size_t)b * SEQ + q) * DMODEL + h * 64 + lc;
#pragma unroll
        for (int n = 0; n < 4; ++n) {
            float o = ctx[n][r] * inv;
            ushort hh = f2bf(o);
            ctx_hi[base + 16 * n] = hh;
            ctx_lo[base + 16 * n] = f2bf(o - bf2f(hh));
        }
    }
}

// ------------- fused residual + LayerNorm (+ optional bf16 hi/lo split of output) -------------
__global__ __launch_bounds__(256)
void ln_kernel(const float* __restrict__ X, const float* __restrict__ R,
               const float* __restrict__ gw, const float* __restrict__ bw,
               float* __restrict__ out, ushort* __restrict__ ohi, ushort* __restrict__ olo) {
    __shared__ float red[8];
    const int i = blockIdx.x;
    const int t = threadIdx.x;
    const float* xp = X + (size_t)i * DMODEL;
    const float* rp = R + (size_t)i * DMODEL;
    float4 xv = *(const float4*)(xp + t * 4);
    float4 rv = *(const float4*)(rp + t * 4);
    float v0 = xv.x + rv.x, v1 = xv.y + rv.y, v2 = xv.z + rv.z, v3 = xv.w + rv.w;
    float sum = v0 + v1 + v2 + v3;
    float sq  = v0 * v0 + v1 * v1 + v2 * v2 + v3 * v3;
#pragma unroll
    for (int off = 32; off > 0; off >>= 1) {
        sum += __shfl_down(sum, off, 64);
        sq  += __shfl_down(sq,  off, 64);
    }
    int wid = t >> 6;
    if ((t & 63) == 0) { red[wid] = sum; red[4 + wid] = sq; }
    __syncthreads();
    sum = red[0] + red[1] + red[2] + red[3];
    sq  = red[4] + red[5] + red[6] + red[7];
    float mu   = sum * (1.0f / DMODEL);
    float var  = sq * (1.0f / DMODEL) - mu * mu;
    float rstd = rsqrtf(var + 1e-5f);
    float4 gv = *(const float4*)(gw + t * 4);
    float4 bv = *(const float4*)(bw + t * 4);
    float4 o;
    o.x = (v0 - mu) * rstd * gv.x + bv.x;
    o.y = (v1 - mu) * rstd * gv.y + bv.y;
    o.z = (v2 - mu) * rstd * gv.z + bv.z;
    o.w = (v3 - mu) * rstd * gv.w + bv.w;
    *(float4*)(out + (size_t)i * DMODEL + t * 4) = o;
    if (ohi) {
        ushort4 h, l;
        h.x = f2bf(o.x); l.x = f2bf(o.x - bf2f(h.x));
        h.y = f2bf(o.y); l.y = f2bf(o.y - bf2f(h.y));
        h.z = f2bf(o.z); l.z = f2bf(o.z - bf2f(h.z));
        h.w = f2bf(o.w); l.w = f2bf(o.w - bf2f(h.w));
        size_t off = (size_t)i * DMODEL + t * 4;
        *(ushort4*)&ohi[off] = h;
        *(ushort4*)&olo[off] = l;
    }
}

extern "C" void kernel_launch(void* const* d_in, const int* in_sizes, int n_in,
                              void* d_out, int out_size, void* d_ws, size_t ws_size,
                              hipStream_t stream) {
    const float* x   = (const float*)d_in[0];
    const float* Wq  = (const float*)d_in[1];
    const float* Wk  = (const float*)d_in[2];
    const float* Wv  = (const float*)d_in[3];
    const float* Wo  = (const float*)d_in[4];
    const float* Mk  = (const float*)d_in[5];
    const float* g1  = (const float*)d_in[6];
    const float* bl1 = (const float*)d_in[7];
    const float* g2  = (const float*)d_in[8];
    const float* bl2 = (const float*)d_in[9];
    const float* W1  = (const float*)d_in[10];
    const float* bf1 = (const float*)d_in[11];
    const float* W2  = (const float*)d_in[12];
    const float* bf2 = (const float*)d_in[13];
    float* out = (float*)d_out;
    char* wsb  = (char*)d_ws;

    const size_t MB = 1024 * 1024;
    // ---- workspace layout, peak 192 MB (lifetime-overlapped) ----
    // [0,48)    qkv fp32             -> dead after headproj+vsplit; h1_hi reuses [0,32)
    // [48,64)   qmh/qml              -> dead after attn; h1_lo reuses [32,64)
    // [64,80)   kmh/kml              -> dead after attn; w2T reuses (split AFTER attn)
    // [80,96)   vth/vtl              -> dead after attn
    // [96,112)  x_hi/x_lo            -> dead after QKV; ctx planes reuse
    // [112,128) wo_out fp32          -> dead after LN1; ff2 reuses
    // [128,144) y fp32
    // [144,160) y_hi/y_lo
    // [160,192) wqkvT + woT + w1T planes
    float*  qkv   = (float*)(wsb + 0 * MB);
    ushort* qmh   = (ushort*)(wsb + 48 * MB);
    ushort* qml   = (ushort*)(wsb + 56 * MB);
    ushort* kmh   = (ushort*)(wsb + 64 * MB);
    ushort* kml   = (ushort*)(wsb + 72 * MB);
    ushort* vth   = (ushort*)(wsb + 80 * MB);
    ushort* vtl   = (ushort*)(wsb + 88 * MB);
    ushort* x_hi  = (ushort*)(wsb + 96 * MB);
    ushort* x_lo  = (ushort*)(wsb + 104 * MB);
    ushort* ctx_hi = x_hi;                       // x planes dead after QKV
    ushort* ctx_lo = x_lo;
    float*  wo_out = (float*)(wsb + 112 * MB);
    float*  ff2    = wo_out;                     // wo_out dead after LN1
    float*  y      = (float*)(wsb + 128 * MB);
    ushort* y_hi   = (ushort*)(wsb + 144 * MB);
    ushort* y_lo   = (ushort*)(wsb + 152 * MB);
    ushort* wqkvT_hi = (ushort*)(wsb + 160 * MB);   // 3072x1024 = 6 MB
    ushort* wqkvT_lo = (ushort*)(wsb + 166 * MB);
    ushort* woT_hi   = (ushort*)(wsb + 172 * MB);   // 2 MB
    ushort* woT_lo   = (ushort*)(wsb + 174 * MB);
    ushort* w1T_hi   = (ushort*)(wsb + 176 * MB);   // 8 MB
    ushort* w1T_lo   = (ushort*)(wsb + 184 * MB);
    ushort* w2T_hi   = (ushort*)(wsb + 64 * MB);    // over dead km planes (split after attn)
    ushort* w2T_lo   = (ushort*)(wsb + 72 * MB);
    ushort* h1_hi    = (ushort*)(wsb + 0 * MB);     // 32 MB over dead qkv
    ushort* h1_lo    = (ushort*)(wsb + 32 * MB);    // 32 MB over dead qkv tail + qm planes

    dim3 blk(256);
    dim3 hgrid(SEQ / 64, NH, BATCH);
    // --- weight prep (W2 deferred until km planes are dead) ---
    splitT_kernel<<<dim3(16, 16), blk, 0, stream>>>(Wq, wqkvT_hi, wqkvT_lo, DMODEL, DMODEL);
    splitT_kernel<<<dim3(16, 16), blk, 0, stream>>>(Wk, wqkvT_hi + (size_t)1024 * 1024, wqkvT_lo + (size_t)1024 * 1024, DMODEL, DMODEL);
    splitT_kernel<<<dim3(16, 16), blk, 0, stream>>>(Wv, wqkvT_hi + (size_t)2048 * 1024, wqkvT_lo + (size_t)2048 * 1024, DMODEL, DMODEL);
    splitT_kernel<<<dim3(16, 16), blk, 0, stream>>>(Wo, woT_hi, woT_lo, DMODEL, DMODEL);
    splitT_kernel<<<dim3(64, 16), blk, 0, stream>>>(W1, w1T_hi, w1T_lo, DMODEL, FDIM);
    // --- x split + fused QKV projection ---
    splitA_kernel<<<dim3(4096), blk, 0, stream>>>(x, x_hi, x_lo, NROWS * DMODEL / 4);
    mfma_gemm<0, 0><<<dim3(24, 32), blk, 0, stream>>>(x_hi, x_lo, wqkvT_hi, wqkvT_lo,
                                                      nullptr, qkv, nullptr, nullptr, DMODEL, 3072);
    // --- memory-key projections -> bf16 planes ---
    headproj_kernel<<<hgrid, blk, 0, stream>>>(qkv + 0,    3072, Mk, qmh, qml);
    headproj_kernel<<<hgrid, blk, 0, stream>>>(qkv + 1024, 3072, Mk, kmh, kml);
    // --- V split+transpose -> (b,h,d,s) planes ---
    vsplitT_kernel<<<hgrid, blk, 0, stream>>>(qkv, vth, vtl);
    // --- MFMA flash attention -> ctx planes ---
    attn_mfma<<<hgrid, blk, 0, stream>>>(qmh, qml, kmh, kml, vth, vtl, ctx_hi, ctx_lo);
    // --- W2 split (km planes now dead) ---
    splitT_kernel<<<dim3(16, 64), blk, 0, stream>>>(W2, w2T_hi, w2T_lo, FDIM, DMODEL);
    // --- Wo projection ---
    mfma_gemm<0, 0><<<dim3(8, 32), blk, 0, stream>>>(ctx_hi, ctx_lo, woT_hi, woT_lo,
                                                     nullptr, wo_out, nullptr, nullptr, DMODEL, DMODEL);
    // --- LN1 (+ split of y) ---
    ln_kernel<<<dim3(NROWS), blk, 0, stream>>>(x, wo_out, g1, bl1, y, y_hi, y_lo);
    // --- FFN1: bias + GELU + split fused ---
    mfma_gemm<1, 1><<<dim3(32, 32), blk, 0, stream>>>(y_hi, y_lo, w1T_hi, w1T_lo,
                                                      bf1, nullptr, h1_hi, h1_lo, DMODEL, FDIM);
    // --- FFN2 ---
    mfma_gemm<0, 0><<<dim3(8, 32), blk, 0, stream>>>(h1_hi, h1_lo, w2T_hi, w2T_lo,
                                                     bf2, ff2, nullptr, nullptr, FDIM, DMODEL);
    // --- LN2 -> out ---
    ln_kernel<<<dim3(NROWS), blk, 0, stream>>>(y, ff2, g2, bl2, out, nullptr, nullptr);
}

// Round 11
// 1200.886 us; speedup vs baseline: 2.3204x; 1.0455x over previous
//
#include <hip/hip_runtime.h>
#include <math.h>

#define NH 16
#define DH 64
#define MDIM 64
#define DMODEL 1024
#define FDIM 4096
#define BATCH 2
#define SEQ 2048
#define NROWS (BATCH*SEQ)   // 4096

typedef short bf16x8 __attribute__((ext_vector_type(8)));
typedef float f32x4 __attribute__((ext_vector_type(4)));

__device__ __forceinline__ float gelu_f(float v) {
    return 0.5f * v * (1.0f + erff(v * 0.70710678118654752f));
}
__device__ __forceinline__ ushort f2bf(float f) {
    union { float f; unsigned u; } v; v.f = f;
    unsigned r = v.u + 0x7fffu + ((v.u >> 16) & 1u);
    return (ushort)(r >> 16);
}
__device__ __forceinline__ float bf2f(ushort h) {
    union { unsigned u; float f; } v; v.u = ((unsigned)h) << 16;
    return v.f;
}
__device__ __forceinline__ void gl_lds16(const ushort* g, ushort* l) {
    __builtin_amdgcn_global_load_lds((const __attribute__((address_space(1))) void*)g,
                                     (__attribute__((address_space(3))) void*)l, 16, 0, 0);
}

// ---------------- split (no transpose): fp32 -> hi/lo bf16 planes ----------------
__global__ __launch_bounds__(256)
void splitA_kernel(const float* __restrict__ X, ushort* __restrict__ hi,
                   ushort* __restrict__ lo, int n4) {
    int i = blockIdx.x * 256 + threadIdx.x;
    if (i >= n4) return;
    float4 v = ((const float4*)X)[i];
    ushort4 h, l;
    h.x = f2bf(v.x); l.x = f2bf(v.x - bf2f(h.x));
    h.y = f2bf(v.y); l.y = f2bf(v.y - bf2f(h.y));
    h.z = f2bf(v.z); l.z = f2bf(v.z - bf2f(h.z));
    h.w = f2bf(v.w); l.w = f2bf(v.w - bf2f(h.w));
    ((ushort4*)hi)[i] = h;
    ((ushort4*)lo)[i] = l;
}

// ---------------- split + transpose: W (K x N fp32) -> WT hi/lo (N x K bf16) ----------------
__global__ __launch_bounds__(256)
void splitT_kernel(const float* __restrict__ W, ushort* __restrict__ Thi,
                   ushort* __restrict__ Tlo, int K, int N) {
    __shared__ float tile[64][65];
    const int n0 = blockIdx.x * 64;
    const int k0 = blockIdx.y * 64;
    const int t  = threadIdx.x;
    const int r  = t >> 4;            // 0..15
    const int c4 = (t & 15) * 4;
#pragma unroll
    for (int i = 0; i < 4; ++i) {
        int row = r + i * 16;         // k_local
        float4 v = *(const float4*)&W[(size_t)(k0 + row) * N + n0 + c4];
        tile[c4 + 0][row] = v.x;
        tile[c4 + 1][row] = v.y;
        tile[c4 + 2][row] = v.z;
        tile[c4 + 3][row] = v.w;
    }
    __syncthreads();
#pragma unroll
    for (int i = 0; i < 4; ++i) {
        int row = r + i * 16;         // n_local
        float a = tile[row][c4 + 0], b = tile[row][c4 + 1];
        float c = tile[row][c4 + 2], d = tile[row][c4 + 3];
        ushort4 h, l;
        h.x = f2bf(a); l.x = f2bf(a - bf2f(h.x));
        h.y = f2bf(b); l.y = f2bf(b - bf2f(h.y));
        h.z = f2bf(c); l.z = f2bf(c - bf2f(h.z));
        h.w = f2bf(d); l.w = f2bf(d - bf2f(h.w));
        size_t off = (size_t)(n0 + row) * K + k0 + c4;
        *(ushort4*)&Thi[off] = h;
        *(ushort4*)&Tlo[off] = l;
    }
}

// ---------------- bf16x3 MFMA GEMM (validated Round 7) ----------------
template<int ACT, int SPLIT_OUT>
__global__ __launch_bounds__(256)
void mfma_gemm(const ushort* __restrict__ Ahi, const ushort* __restrict__ Alo,
               const ushort* __restrict__ BThi, const ushort* __restrict__ BTlo,
               const float* __restrict__ bias, float* __restrict__ C,
               ushort* __restrict__ Chi, ushort* __restrict__ Clo,
               int K, int N) {
    __shared__ ushort As[128 * 32];
    __shared__ ushort Bs[128 * 32];
    const int t    = threadIdx.x;
    const int lane = t & 63;
    const int wid  = t >> 6;
    const int wr   = wid >> 1;
    const int wc   = wid & 1;
    const int i0   = blockIdx.y * 128;
    const int n0   = blockIdx.x * 128;
    const int srow = t >> 2;
    const int scol = (t & 3) * 8;
    ushort* aDst0 = As + t * 8;
    ushort* aDst1 = As + 2048 + t * 8;
    ushort* bDst0 = Bs + t * 8;
    ushort* bDst1 = Bs + 2048 + t * 8;

    f32x4 acc[4][4];
#pragma unroll
    for (int m = 0; m < 4; ++m)
#pragma unroll
        for (int n = 0; n < 4; ++n) {
            acc[m][n][0] = 0.f; acc[m][n][1] = 0.f;
            acc[m][n][2] = 0.f; acc[m][n][3] = 0.f;
        }

    const int aOff = (wr * 64 + (lane & 15)) * 32 + (lane >> 4) * 8;
    const int bOff = (wc * 64 + (lane & 15)) * 32 + (lane >> 4) * 8;

    for (int seg = 0; seg < 3; ++seg) {
        const ushort* Ab = (seg == 1) ? Alo : Ahi;
        const ushort* Bb = (seg == 2) ? BTlo : BThi;
        const ushort* Ap0 = Ab + (size_t)(i0 + srow) * K + scol;
        const ushort* Ap1 = Ap0 + (size_t)64 * K;
        const ushort* Bp0 = Bb + (size_t)(n0 + srow) * K + scol;
        const ushort* Bp1 = Bp0 + (size_t)64 * K;
        for (int k0 = 0; k0 < K; k0 += 32) {
            __syncthreads();
            gl_lds16(Ap0 + k0, aDst0);
            gl_lds16(Ap1 + k0, aDst1);
            gl_lds16(Bp0 + k0, bDst0);
            gl_lds16(Bp1 + k0, bDst1);
            __syncthreads();
            bf16x8 af[4], bfr[4];
#pragma unroll
            for (int m = 0; m < 4; ++m)
                af[m] = *(const bf16x8*)&As[aOff + m * 16 * 32];
#pragma unroll
            for (int n = 0; n < 4; ++n)
                bfr[n] = *(const bf16x8*)&Bs[bOff + n * 16 * 32];
#pragma unroll
            for (int m = 0; m < 4; ++m)
#pragma unroll
                for (int n = 0; n < 4; ++n)
                    acc[m][n] = __builtin_amdgcn_mfma_f32_16x16x32_bf16(af[m], bfr[n], acc[m][n], 0, 0, 0);
        }
    }

    const int orow  = i0 + wr * 64 + (lane >> 4) * 4;
    const int ocol0 = n0 + wc * 64 + (lane & 15);
#pragma unroll
    for (int n = 0; n < 4; ++n) {
        const int colg = ocol0 + n * 16;
        float bv = bias ? bias[colg] : 0.f;
#pragma unroll
        for (int m = 0; m < 4; ++m) {
#pragma unroll
            for (int r = 0; r < 4; ++r) {
                const int rowg = orow + m * 16 + r;
                float v = acc[m][n][r] + bv;
                if (ACT == 1) v = gelu_f(v);
                size_t off = (size_t)rowg * N + colg;
                if (SPLIT_OUT) {
                    ushort h = f2bf(v);
                    Chi[off] = h;
                    Clo[off] = f2bf(v - bf2f(h));
                } else {
                    C[off] = v;
                }
            }
        }
    }
}

// ------------- per-head projection -> bf16 hi/lo planes (b,h,s,m) -------------
__global__ __launch_bounds__(256)
void headproj_kernel(const float* __restrict__ X, int xstride, const float* __restrict__ Mk,
                     ushort* __restrict__ oh, ushort* __restrict__ ol) {
    __shared__ float Qs[64][65];
    __shared__ float Ms[64][68];
    const int s0 = blockIdx.x * 64;
    const int h  = blockIdx.y;
    const int b  = blockIdx.z;
    const int t  = threadIdx.x;
    const int tc = t & 15, tr = t >> 4;
    const float* xb = X + (size_t)(b * SEQ + s0) * xstride + h * 64;
    const float* mk = Mk + (size_t)h * 64 * 64;
#pragma unroll
    for (int i = 0; i < 4; ++i) {
        int e4  = t + i * 256;
        int row = e4 >> 4;
        int c4  = (e4 & 15) << 2;
        float4 q4 = *(const float4*)(xb + (size_t)row * xstride + c4);
        Qs[c4 + 0][row] = q4.x;
        Qs[c4 + 1][row] = q4.y;
        Qs[c4 + 2][row] = q4.z;
        Qs[c4 + 3][row] = q4.w;
        float4 m4 = *(const float4*)(mk + row * 64 + c4);
        *(float4*)&Ms[row][c4] = m4;
    }
    __syncthreads();
    float acc[4][4] = {};
#pragma unroll 16
    for (int kk = 0; kk < 64; ++kk) {
        float a0 = Qs[kk][tr * 4 + 0];
        float a1 = Qs[kk][tr * 4 + 1];
        float a2 = Qs[kk][tr * 4 + 2];
        float a3 = Qs[kk][tr * 4 + 3];
        float4 b4 = *(const float4*)&Ms[kk][tc * 4];
        acc[0][0] += a0 * b4.x; acc[0][1] += a0 * b4.y; acc[0][2] += a0 * b4.z; acc[0][3] += a0 * b4.w;
        acc[1][0] += a1 * b4.x; acc[1][1] += a1 * b4.y; acc[1][2] += a1 * b4.z; acc[1][3] += a1 * b4.w;
        acc[2][0] += a2 * b4.x; acc[2][1] += a2 * b4.y; acc[2][2] += a2 * b4.z; acc[2][3] += a2 * b4.w;
        acc[3][0] += a3 * b4.x; acc[3][1] += a3 * b4.y; acc[3][2] += a3 * b4.z; acc[3][3] += a3 * b4.w;
    }
    ushort* oph = oh + ((size_t)(b * NH + h) * SEQ + s0) * 64;
    ushort* opl = ol + ((size_t)(b * NH + h) * SEQ + s0) * 64;
#pragma unroll
    for (int i = 0; i < 4; ++i) {
        ushort4 h4, l4;
        h4.x = f2bf(acc[i][0]); l4.x = f2bf(acc[i][0] - bf2f(h4.x));
        h4.y = f2bf(acc[i][1]); l4.y = f2bf(acc[i][1] - bf2f(h4.y));
        h4.z = f2bf(acc[i][2]); l4.z = f2bf(acc[i][2] - bf2f(h4.z));
        h4.w = f2bf(acc[i][3]); l4.w = f2bf(acc[i][3] - bf2f(h4.w));
        *(ushort4*)(oph + (size_t)(tr * 4 + i) * 64 + tc * 4) = h4;
        *(ushort4*)(opl + (size_t)(tr * 4 + i) * 64 + tc * 4) = l4;
    }
}

// ------------- V slice: split + transpose -> vT hi/lo planes (b,h,d,s) -------------
__global__ __launch_bounds__(256)
void vsplitT_kernel(const float* __restrict__ qkv, ushort* __restrict__ vth,
                    ushort* __restrict__ vtl) {
    __shared__ float tile[64][65];
    const int s0 = blockIdx.x * 64;
    const int h  = blockIdx.y;
    const int b  = blockIdx.z;
    const int t  = threadIdx.x;
    const int r  = t >> 4;
    const int c4 = (t & 15) * 4;
    const float* src = qkv + (size_t)(b * SEQ + s0) * 3072 + 2048 + h * 64;
#pragma unroll
    for (int i = 0; i < 4; ++i) {
        int srow = r + i * 16;
        float4 v = *(const float4*)(src + (size_t)srow * 3072 + c4);
        tile[c4 + 0][srow] = v.x;
        tile[c4 + 1][srow] = v.y;
        tile[c4 + 2][srow] = v.z;
        tile[c4 + 3][srow] = v.w;
    }
    __syncthreads();
    const size_t obase = (size_t)(b * NH + h) * 64 * SEQ + s0;
#pragma unroll
    for (int i = 0; i < 4; ++i) {
        int d = r + i * 16;
        float a = tile[d][c4 + 0], bb = tile[d][c4 + 1];
        float c = tile[d][c4 + 2], dd = tile[d][c4 + 3];
        ushort4 h4, l4;
        h4.x = f2bf(a);  l4.x = f2bf(a - bf2f(h4.x));
        h4.y = f2bf(bb); l4.y = f2bf(bb - bf2f(h4.y));
        h4.z = f2bf(c);  l4.z = f2bf(c - bf2f(h4.z));
        h4.w = f2bf(dd); l4.w = f2bf(dd - bf2f(h4.w));
        *(ushort4*)&vth[obase + (size_t)d * SEQ + c4] = h4;
        *(ushort4*)&vtl[obase + (size_t)d * SEQ + c4] = l4;
    }
}

// ------------- MFMA flash attention, bf16x3, 1-wave blocks + prefetch -------------
// grid (SEQ/16, NH, BATCH), 64 threads = 1 wave owning 16 q-rows.
// Current-tile K_lo/V_hi loads issued at loop top (hidden under QK MFMAs);
// next-tile K_hi/K_lo prefetched before softmax (hidden under softmax+PV);
// V_lo issued before P-LDS read (hidden under hi-PV MFMAs). Same math as R8.
__global__ __launch_bounds__(64)
void attn_mfma(const ushort* __restrict__ qmh, const ushort* __restrict__ qml,
               const ushort* __restrict__ kmh, const ushort* __restrict__ kml,
               const ushort* __restrict__ vth, const ushort* __restrict__ vtl,
               ushort* __restrict__ ctx_hi, ushort* __restrict__ ctx_lo) {
    __shared__ ushort ph[1024];   // [16q x 64kv] hi, XOR-swizzled
    __shared__ ushort pl[1024];   // lo
    const int q0 = blockIdx.x * 16;
    const int h  = blockIdx.y;
    const int b  = blockIdx.z;
    const int lane = threadIdx.x;
    const int rg = lane >> 4;      // 0..3
    const int lc = lane & 15;
    const size_t bh = (size_t)b * NH + h;

    const ushort* qb_h = qmh + (bh * SEQ + q0 + lc) * 64 + rg * 8;
    const ushort* qb_l = qml + (bh * SEQ + q0 + lc) * 64 + rg * 8;
    bf16x8 qfh[2], qfl[2];
    qfh[0] = *(const bf16x8*)(qb_h);
    qfh[1] = *(const bf16x8*)(qb_h + 32);
    qfl[0] = *(const bf16x8*)(qb_l);
    qfl[1] = *(const bf16x8*)(qb_l + 32);

    const ushort* kb_h = kmh + (bh * SEQ + lc) * 64 + rg * 8;
    const ushort* kb_l = kml + (bh * SEQ + lc) * 64 + rg * 8;
    const ushort* vb_h = vth + (bh * 64 + lc) * SEQ + rg * 8;
    const ushort* vb_l = vtl + (bh * 64 + lc) * SEQ + rg * 8;

    f32x4 ctx[4];
#pragma unroll
    for (int n = 0; n < 4; ++n) { ctx[n][0] = 0.f; ctx[n][1] = 0.f; ctx[n][2] = 0.f; ctx[n][3] = 0.f; }
    float m_r[4] = { -INFINITY, -INFINITY, -INFINITY, -INFINITY };
    float l_r[4] = { 0.f, 0.f, 0.f, 0.f };

    // prefetch tile 0 K (hi+lo)
    bf16x8 kh[4][2], kl[4][2];
#pragma unroll
    for (int n = 0; n < 4; ++n) {
        kh[n][0] = *(const bf16x8*)(kb_h + (size_t)(16 * n) * 64);
        kh[n][1] = *(const bf16x8*)(kb_h + (size_t)(16 * n) * 64 + 32);
        kl[n][0] = *(const bf16x8*)(kb_l + (size_t)(16 * n) * 64);
        kl[n][1] = *(const bf16x8*)(kb_l + (size_t)(16 * n) * 64 + 32);
    }

    for (int kv0 = 0; kv0 < SEQ; kv0 += 64) {
        // ---- V_hi loads early: consumed only after softmax ----
        bf16x8 vh[4][2];
#pragma unroll
        for (int n = 0; n < 4; ++n) {
            vh[n][0] = *(const bf16x8*)(vb_h + (size_t)(16 * n) * SEQ + kv0);
            vh[n][1] = *(const bf16x8*)(vb_h + (size_t)(16 * n) * SEQ + kv0 + 32);
        }
        // ---- QK^T (bf16x3) with current-tile kh/kl ----
        f32x4 sacc[4];
#pragma unroll
        for (int n = 0; n < 4; ++n) { sacc[n][0] = 0.f; sacc[n][1] = 0.f; sacc[n][2] = 0.f; sacc[n][3] = 0.f; }
#pragma unroll
        for (int n = 0; n < 4; ++n) {
            sacc[n] = __builtin_amdgcn_mfma_f32_16x16x32_bf16(qfh[0], kh[n][0], sacc[n], 0, 0, 0);
            sacc[n] = __builtin_amdgcn_mfma_f32_16x16x32_bf16(qfh[1], kh[n][1], sacc[n], 0, 0, 0);
            sacc[n] = __builtin_amdgcn_mfma_f32_16x16x32_bf16(qfl[0], kh[n][0], sacc[n], 0, 0, 0);
            sacc[n] = __builtin_amdgcn_mfma_f32_16x16x32_bf16(qfl[1], kh[n][1], sacc[n], 0, 0, 0);
            sacc[n] = __builtin_amdgcn_mfma_f32_16x16x32_bf16(qfh[0], kl[n][0], sacc[n], 0, 0, 0);
            sacc[n] = __builtin_amdgcn_mfma_f32_16x16x32_bf16(qfh[1], kl[n][1], sacc[n], 0, 0, 0);
        }
        // ---- prefetch next tile's K (hi+lo): latency hidden under softmax+PV ----
        if (kv0 + 64 < SEQ) {
            const size_t nb = (size_t)(kv0 + 64) * 64;
#pragma unroll
            for (int n = 0; n < 4; ++n) {
                kh[n][0] = *(const bf16x8*)(kb_h + nb + (size_t)(16 * n) * 64);
                kh[n][1] = *(const bf16x8*)(kb_h + nb + (size_t)(16 * n) * 64 + 32);
                kl[n][0] = *(const bf16x8*)(kb_l + nb + (size_t)(16 * n) * 64);
                kl[n][1] = *(const bf16x8*)(kb_l + nb + (size_t)(16 * n) * 64 + 32);
            }
        }
        // ---- online softmax (per q-row rg*4+r; reduce over 16-lane group) ----
#pragma unroll
        for (int r = 0; r < 4; ++r) {
            float s0 = sacc[0][r] * 0.125f;
            float s1 = sacc[1][r] * 0.125f;
            float s2 = sacc[2][r] * 0.125f;
            float s3 = sacc[3][r] * 0.125f;
            float pm = fmaxf(fmaxf(s0, s1), fmaxf(s2, s3));
            pm = fmaxf(pm, __shfl_xor(pm, 1));
            pm = fmaxf(pm, __shfl_xor(pm, 2));
            pm = fmaxf(pm, __shfl_xor(pm, 4));
            pm = fmaxf(pm, __shfl_xor(pm, 8));
            float mnew  = fmaxf(m_r[r], pm);
            float alpha = __expf(m_r[r] - mnew);
            m_r[r] = mnew;
            float p0 = __expf(s0 - mnew);
            float p1 = __expf(s1 - mnew);
            float p2 = __expf(s2 - mnew);
            float p3 = __expf(s3 - mnew);
            float rs = p0 + p1 + p2 + p3;
            rs += __shfl_xor(rs, 1);
            rs += __shfl_xor(rs, 2);
            rs += __shfl_xor(rs, 4);
            rs += __shfl_xor(rs, 8);
            l_r[r] = l_r[r] * alpha + rs;
            ctx[0][r] *= alpha; ctx[1][r] *= alpha; ctx[2][r] *= alpha; ctx[3][r] *= alpha;
            const int q = rg * 4 + r;
            const int swz = (q & 7) << 3;
            const int rowb = q * 64;
            ushort hh;
            hh = f2bf(p0); ph[(rowb + lc)      ^ swz] = hh; pl[(rowb + lc)      ^ swz] = f2bf(p0 - bf2f(hh));
            hh = f2bf(p1); ph[(rowb + lc + 16) ^ swz] = hh; pl[(rowb + lc + 16) ^ swz] = f2bf(p1 - bf2f(hh));
            hh = f2bf(p2); ph[(rowb + lc + 32) ^ swz] = hh; pl[(rowb + lc + 32) ^ swz] = f2bf(p2 - bf2f(hh));
            hh = f2bf(p3); ph[(rowb + lc + 48) ^ swz] = hh; pl[(rowb + lc + 48) ^ swz] = f2bf(p3 - bf2f(hh));
        }
        // ---- V_lo loads: consumed after the 16 hi-PV MFMAs ----
        bf16x8 vl[4][2];
#pragma unroll
        for (int n = 0; n < 4; ++n) {
            vl[n][0] = *(const bf16x8*)(vb_l + (size_t)(16 * n) * SEQ + kv0);
            vl[n][1] = *(const bf16x8*)(vb_l + (size_t)(16 * n) * SEQ + kv0 + 32);
        }
        // ---- PV (bf16x3): P fragments via wave-private LDS transpose ----
        bf16x8 pah[2], pal[2];
        {
            const int swz = (lc & 7) << 3;
            pah[0] = *(const bf16x8*)&ph[(lc * 64 + rg * 8)      ^ swz];
            pah[1] = *(const bf16x8*)&ph[(lc * 64 + rg * 8 + 32) ^ swz];
            pal[0] = *(const bf16x8*)&pl[(lc * 64 + rg * 8)      ^ swz];
            pal[1] = *(const bf16x8*)&pl[(lc * 64 + rg * 8 + 32) ^ swz];
        }
#pragma unroll
        for (int n = 0; n < 4; ++n) {
            ctx[n] = __builtin_amdgcn_mfma_f32_16x16x32_bf16(pah[0], vh[n][0], ctx[n], 0, 0, 0);
            ctx[n] = __builtin_amdgcn_mfma_f32_16x16x32_bf16(pah[1], vh[n][1], ctx[n], 0, 0, 0);
            ctx[n] = __builtin_amdgcn_mfma_f32_16x16x32_bf16(pal[0], vh[n][0], ctx[n], 0, 0, 0);
            ctx[n] = __builtin_amdgcn_mfma_f32_16x16x32_bf16(pal[1], vh[n][1], ctx[n], 0, 0, 0);
        }
#pragma unroll
        for (int n = 0; n < 4; ++n) {
            ctx[n] = __builtin_amdgcn_mfma_f32_16x16x32_bf16(pah[0], vl[n][0], ctx[n], 0, 0, 0);
            ctx[n] = __builtin_amdgcn_mfma_f32_16x16x32_bf16(pah[1], vl[n][1], ctx[n], 0, 0, 0);
        }
    }
    // ---- epilogue: normalize, write ctx hi/lo planes at (b,s,h*64+d) ----
#pragma unroll
    for (int r = 0; r < 4; ++r) {
        float inv = 1.0f / l_r[r];
        const int q = q0 + rg * 4 + r;
        size_t base = ((size_t)b * SEQ + q) * DMODEL + h * 64 + lc;
#pragma unroll
        for (int n = 0; n < 4; ++n) {
            float o = ctx[n][r] * inv;
            ushort hh = f2bf(o);
            ctx_hi[base + 16 * n] = hh;
            ctx_lo[base + 16 * n] = f2bf(o - bf2f(hh));
        }
    }
}

// ------------- fused residual + LayerNorm (+ optional bf16 hi/lo split of output) -------------
__global__ __launch_bounds__(256)
void ln_kernel(const float* __restrict__ X, const float* __restrict__ R,
               const float* __restrict__ gw, const float* __restrict__ bw,
               float* __restrict__ out, ushort* __restrict__ ohi, ushort* __restrict__ olo) {
    __shared__ float red[8];
    const int i = blockIdx.x;
    const int t = threadIdx.x;
    const float* xp = X + (size_t)i * DMODEL;
    const float* rp = R + (size_t)i * DMODEL;
    float4 xv = *(const float4*)(xp + t * 4);
    float4 rv = *(const float4*)(rp + t * 4);
    float v0 = xv.x + rv.x, v1 = xv.y + rv.y, v2 = xv.z + rv.z, v3 = xv.w + rv.w;
    float sum = v0 + v1 + v2 + v3;
    float sq  = v0 * v0 + v1 * v1 + v2 * v2 + v3 * v3;
#pragma unroll
    for (int off = 32; off > 0; off >>= 1) {
        sum += __shfl_down(sum, off, 64);
        sq  += __shfl_down(sq,  off, 64);
    }
    int wid = t >> 6;
    if ((t & 63) == 0) { red[wid] = sum; red[4 + wid] = sq; }
    __syncthreads();
    sum = red[0] + red[1] + red[2] + red[3];
    sq  = red[4] + red[5] + red[6] + red[7];
    float mu   = sum * (1.0f / DMODEL);
    float var  = sq * (1.0f / DMODEL) - mu * mu;
    float rstd = rsqrtf(var + 1e-5f);
    float4 gv = *(const float4*)(gw + t * 4);
    float4 bv = *(const float4*)(bw + t * 4);
    float4 o;
    o.x = (v0 - mu) * rstd * gv.x + bv.x;
    o.y = (v1 - mu) * rstd * gv.y + bv.y;
    o.z = (v2 - mu) * rstd * gv.z + bv.z;
    o.w = (v3 - mu) * rstd * gv.w + bv.w;
    *(float4*)(out + (size_t)i * DMODEL + t * 4) = o;
    if (ohi) {
        ushort4 h, l;
        h.x = f2bf(o.x); l.x = f2bf(o.x - bf2f(h.x));
        h.y = f2bf(o.y); l.y = f2bf(o.y - bf2f(h.y));
        h.z = f2bf(o.z); l.z = f2bf(o.z - bf2f(h.z));
        h.w = f2bf(o.w); l.w = f2bf(o.w - bf2f(h.w));
        size_t off = (size_t)i * DMODEL + t * 4;
        *(ushort4*)&ohi[off] = h;
        *(ushort4*)&olo[off] = l;
    }
}

extern "C" void kernel_launch(void* const* d_in, const int* in_sizes, int n_in,
                              void* d_out, int out_size, void* d_ws, size_t ws_size,
                              hipStream_t stream) {
    const float* x   = (const float*)d_in[0];
    const float* Wq  = (const float*)d_in[1];
    const float* Wk  = (const float*)d_in[2];
    const float* Wv  = (const float*)d_in[3];
    const float* Wo  = (const float*)d_in[4];
    const float* Mk  = (const float*)d_in[5];
    const float* g1  = (const float*)d_in[6];
    const float* bl1 = (const float*)d_in[7];
    const float* g2  = (const float*)d_in[8];
    const float* bl2 = (const float*)d_in[9];
    const float* W1  = (const float*)d_in[10];
    const float* bf1 = (const float*)d_in[11];
    const float* W2  = (const float*)d_in[12];
    const float* bf2 = (const float*)d_in[13];
    float* out = (float*)d_out;
    char* wsb  = (char*)d_ws;

    const size_t MB = 1024 * 1024;
    // ---- workspace layout, peak 192 MB (lifetime-overlapped; validated R8) ----
    float*  qkv   = (float*)(wsb + 0 * MB);
    ushort* qmh   = (ushort*)(wsb + 48 * MB);
    ushort* qml   = (ushort*)(wsb + 56 * MB);
    ushort* kmh   = (ushort*)(wsb + 64 * MB);
    ushort* kml   = (ushort*)(wsb + 72 * MB);
    ushort* vth   = (ushort*)(wsb + 80 * MB);
    ushort* vtl   = (ushort*)(wsb + 88 * MB);
    ushort* x_hi  = (ushort*)(wsb + 96 * MB);
    ushort* x_lo  = (ushort*)(wsb + 104 * MB);
    ushort* ctx_hi = x_hi;                       // x planes dead after QKV
    ushort* ctx_lo = x_lo;
    float*  wo_out = (float*)(wsb + 112 * MB);
    float*  ff2    = wo_out;                     // wo_out dead after LN1
    float*  y      = (float*)(wsb + 128 * MB);
    ushort* y_hi   = (ushort*)(wsb + 144 * MB);
    ushort* y_lo   = (ushort*)(wsb + 152 * MB);
    ushort* wqkvT_hi = (ushort*)(wsb + 160 * MB);   // 3072x1024 = 6 MB
    ushort* wqkvT_lo = (ushort*)(wsb + 166 * MB);
    ushort* woT_hi   = (ushort*)(wsb + 172 * MB);   // 2 MB
    ushort* woT_lo   = (ushort*)(wsb + 174 * MB);
    ushort* w1T_hi   = (ushort*)(wsb + 176 * MB);   // 8 MB
    ushort* w1T_lo   = (ushort*)(wsb + 184 * MB);
    ushort* w2T_hi   = (ushort*)(wsb + 64 * MB);    // over dead km planes (split after attn)
    ushort* w2T_lo   = (ushort*)(wsb + 72 * MB);
    ushort* h1_hi    = (ushort*)(wsb + 0 * MB);     // 32 MB over dead qkv
    ushort* h1_lo    = (ushort*)(wsb + 32 * MB);

    dim3 blk(256);
    dim3 hgrid(SEQ / 64, NH, BATCH);
    // --- weight prep (W2 deferred until km planes are dead) ---
    splitT_kernel<<<dim3(16, 16), blk, 0, stream>>>(Wq, wqkvT_hi, wqkvT_lo, DMODEL, DMODEL);
    splitT_kernel<<<dim3(16, 16), blk, 0, stream>>>(Wk, wqkvT_hi + (size_t)1024 * 1024, wqkvT_lo + (size_t)1024 * 1024, DMODEL, DMODEL);
    splitT_kernel<<<dim3(16, 16), blk, 0, stream>>>(Wv, wqkvT_hi + (size_t)2048 * 1024, wqkvT_lo + (size_t)2048 * 1024, DMODEL, DMODEL);
    splitT_kernel<<<dim3(16, 16), blk, 0, stream>>>(Wo, woT_hi, woT_lo, DMODEL, DMODEL);
    splitT_kernel<<<dim3(64, 16), blk, 0, stream>>>(W1, w1T_hi, w1T_lo, DMODEL, FDIM);
    // --- x split + fused QKV projection ---
    splitA_kernel<<<dim3(4096), blk, 0, stream>>>(x, x_hi, x_lo, NROWS * DMODEL / 4);
    mfma_gemm<0, 0><<<dim3(24, 32), blk, 0, stream>>>(x_hi, x_lo, wqkvT_hi, wqkvT_lo,
                                                      nullptr, qkv, nullptr, nullptr, DMODEL, 3072);
    // --- memory-key projections -> bf16 planes ---
    headproj_kernel<<<hgrid, blk, 0, stream>>>(qkv + 0,    3072, Mk, qmh, qml);
    headproj_kernel<<<hgrid, blk, 0, stream>>>(qkv + 1024, 3072, Mk, kmh, kml);
    // --- V split+transpose -> (b,h,d,s) planes ---
    vsplitT_kernel<<<hgrid, blk, 0, stream>>>(qkv, vth, vtl);
    // --- MFMA flash attention (1-wave blocks) -> ctx planes ---
    attn_mfma<<<dim3(SEQ / 16, NH, BATCH), dim3(64), 0, stream>>>(qmh, qml, kmh, kml, vth, vtl, ctx_hi, ctx_lo);
    // --- W2 split (km planes now dead) ---
    splitT_kernel<<<dim3(16, 64), blk, 0, stream>>>(W2, w2T_hi, w2T_lo, FDIM, DMODEL);
    // --- Wo projection ---
    mfma_gemm<0, 0><<<dim3(8, 32), blk, 0, stream>>>(ctx_hi, ctx_lo, woT_hi, woT_lo,
                                                     nullptr, wo_out, nullptr, nullptr, DMODEL, DMODEL);
    // --- LN1 (+ split of y) ---
    ln_kernel<<<dim3(NROWS), blk, 0, stream>>>(x, wo_out, g1, bl1, y, y_hi, y_lo);
    // --- FFN1: bias + GELU + split fused ---
    mfma_gemm<1, 1><<<dim3(32, 32), blk, 0, stream>>>(y_hi, y_lo, w1T_hi, w1T_lo,
                                                      bf1, nullptr, h1_hi, h1_lo, DMODEL, FDIM);
    // --- FFN2 ---
    mfma_gemm<0, 0><<<dim3(8, 32), blk, 0, stream>>>(h1_hi, h1_lo, w2T_hi, w2T_lo,
                                                     bf2, ff2, nullptr, nullptr, FDIM, DMODEL);
    // --- LN2 -> out ---
    ln_kernel<<<dim3(NROWS), blk, 0, stream>>>(y, ff2, g2, bl2, out, nullptr, nullptr);
}

// Round 12
// 1085.226 us; speedup vs baseline: 2.5677x; 1.1066x over previous
//
#include <hip/hip_runtime.h>
#include <math.h>

#define NH 16
#define DH 64
#define MDIM 64
#define DMODEL 1024
#define FDIM 4096
#define BATCH 2
#define SEQ 2048
#define NROWS (BATCH*SEQ)   // 4096

typedef short bf16x8 __attribute__((ext_vector_type(8)));
typedef float f32x4 __attribute__((ext_vector_type(4)));

__device__ __forceinline__ float gelu_f(float v) {
    return 0.5f * v * (1.0f + erff(v * 0.70710678118654752f));
}
__device__ __forceinline__ ushort f2bf(float f) {
    union { float f; unsigned u; } v; v.f = f;
    unsigned r = v.u + 0x7fffu + ((v.u >> 16) & 1u);
    return (ushort)(r >> 16);
}
__device__ __forceinline__ float bf2f(ushort h) {
    union { unsigned u; float f; } v; v.u = ((unsigned)h) << 16;
    return v.f;
}
__device__ __forceinline__ void gl_lds16(const ushort* g, ushort* l) {
    __builtin_amdgcn_global_load_lds((const __attribute__((address_space(1))) void*)g,
                                     (__attribute__((address_space(3))) void*)l, 16, 0, 0);
}

// ---------------- split (no transpose): fp32 -> hi/lo bf16 planes ----------------
__global__ __launch_bounds__(256)
void splitA_kernel(const float* __restrict__ X, ushort* __restrict__ hi,
                   ushort* __restrict__ lo, int n4) {
    int i = blockIdx.x * 256 + threadIdx.x;
    if (i >= n4) return;
    float4 v = ((const float4*)X)[i];
    ushort4 h, l;
    h.x = f2bf(v.x); l.x = f2bf(v.x - bf2f(h.x));
    h.y = f2bf(v.y); l.y = f2bf(v.y - bf2f(h.y));
    h.z = f2bf(v.z); l.z = f2bf(v.z - bf2f(h.z));
    h.w = f2bf(v.w); l.w = f2bf(v.w - bf2f(h.w));
    ((ushort4*)hi)[i] = h;
    ((ushort4*)lo)[i] = l;
}

// ---------------- split + transpose: W (K x N fp32) -> WT hi/lo (N x K bf16) ----------------
__global__ __launch_bounds__(256)
void splitT_kernel(const float* __restrict__ W, ushort* __restrict__ Thi,
                   ushort* __restrict__ Tlo, int K, int N) {
    __shared__ float tile[64][65];
    const int n0 = blockIdx.x * 64;
    const int k0 = blockIdx.y * 64;
    const int t  = threadIdx.x;
    const int r  = t >> 4;            // 0..15
    const int c4 = (t & 15) * 4;
#pragma unroll
    for (int i = 0; i < 4; ++i) {
        int row = r + i * 16;         // k_local
        float4 v = *(const float4*)&W[(size_t)(k0 + row) * N + n0 + c4];
        tile[c4 + 0][row] = v.x;
        tile[c4 + 1][row] = v.y;
        tile[c4 + 2][row] = v.z;
        tile[c4 + 3][row] = v.w;
    }
    __syncthreads();
#pragma unroll
    for (int i = 0; i < 4; ++i) {
        int row = r + i * 16;         // n_local
        float a = tile[row][c4 + 0], b = tile[row][c4 + 1];
        float c = tile[row][c4 + 2], d = tile[row][c4 + 3];
        ushort4 h, l;
        h.x = f2bf(a); l.x = f2bf(a - bf2f(h.x));
        h.y = f2bf(b); l.y = f2bf(b - bf2f(h.y));
        h.z = f2bf(c); l.z = f2bf(c - bf2f(h.z));
        h.w = f2bf(d); l.w = f2bf(d - bf2f(h.w));
        size_t off = (size_t)(n0 + row) * K + k0 + c4;
        *(ushort4*)&Thi[off] = h;
        *(ushort4*)&Tlo[off] = l;
    }
}

// ---------------- bf16x3 MFMA GEMM — single-pass: all 4 planes staged per K-step ----------------
// 48 MFMA between one barrier pair per K-step (was 16 across 3 passes); staging -33%.
template<int ACT, int SPLIT_OUT>
__global__ __launch_bounds__(256)
void mfma_gemm(const ushort* __restrict__ Ahi, const ushort* __restrict__ Alo,
               const ushort* __restrict__ BThi, const ushort* __restrict__ BTlo,
               const float* __restrict__ bias, float* __restrict__ C,
               ushort* __restrict__ Chi, ushort* __restrict__ Clo,
               int K, int N) {
    __shared__ ushort Ah[128 * 32];
    __shared__ ushort Al[128 * 32];
    __shared__ ushort Bh[128 * 32];
    __shared__ ushort Bl[128 * 32];
    const int t    = threadIdx.x;
    const int lane = t & 63;
    const int wid  = t >> 6;
    const int wr   = wid >> 1;
    const int wc   = wid & 1;
    const int i0   = blockIdx.y * 128;
    const int n0   = blockIdx.x * 128;
    const int srow = t >> 2;           // 0..63 staging row
    const int scol = (t & 3) * 8;      // staging bf16 col

    ushort* dAh0 = Ah + t * 8;  ushort* dAh1 = Ah + 2048 + t * 8;
    ushort* dAl0 = Al + t * 8;  ushort* dAl1 = Al + 2048 + t * 8;
    ushort* dBh0 = Bh + t * 8;  ushort* dBh1 = Bh + 2048 + t * 8;
    ushort* dBl0 = Bl + t * 8;  ushort* dBl1 = Bl + 2048 + t * 8;

    const ushort* Aph0 = Ahi + (size_t)(i0 + srow) * K + scol;
    const ushort* Aph1 = Aph0 + (size_t)64 * K;
    const ushort* Apl0 = Alo + (size_t)(i0 + srow) * K + scol;
    const ushort* Apl1 = Apl0 + (size_t)64 * K;
    const ushort* Bph0 = BThi + (size_t)(n0 + srow) * K + scol;
    const ushort* Bph1 = Bph0 + (size_t)64 * K;
    const ushort* Bpl0 = BTlo + (size_t)(n0 + srow) * K + scol;
    const ushort* Bpl1 = Bpl0 + (size_t)64 * K;

    f32x4 acc[4][4];
#pragma unroll
    for (int m = 0; m < 4; ++m)
#pragma unroll
        for (int n = 0; n < 4; ++n) {
            acc[m][n][0] = 0.f; acc[m][n][1] = 0.f;
            acc[m][n][2] = 0.f; acc[m][n][3] = 0.f;
        }

    const int aOff = (wr * 64 + (lane & 15)) * 32 + (lane >> 4) * 8;
    const int bOff = (wc * 64 + (lane & 15)) * 32 + (lane >> 4) * 8;

    for (int k0 = 0; k0 < K; k0 += 32) {
        __syncthreads();                 // previous iter's LDS reads done
        gl_lds16(Aph0 + k0, dAh0);
        gl_lds16(Aph1 + k0, dAh1);
        gl_lds16(Apl0 + k0, dAl0);
        gl_lds16(Apl1 + k0, dAl1);
        gl_lds16(Bph0 + k0, dBh0);
        gl_lds16(Bph1 + k0, dBh1);
        gl_lds16(Bpl0 + k0, dBl0);
        gl_lds16(Bpl1 + k0, dBl1);
        __syncthreads();                 // loads visible (vmcnt drained)
        bf16x8 afh[4], afl[4], bfh[4], bfl[4];
#pragma unroll
        for (int m = 0; m < 4; ++m) {
            afh[m] = *(const bf16x8*)&Ah[aOff + m * 16 * 32];
            afl[m] = *(const bf16x8*)&Al[aOff + m * 16 * 32];
        }
#pragma unroll
        for (int n = 0; n < 4; ++n) {
            bfh[n] = *(const bf16x8*)&Bh[bOff + n * 16 * 32];
            bfl[n] = *(const bf16x8*)&Bl[bOff + n * 16 * 32];
        }
#pragma unroll
        for (int m = 0; m < 4; ++m)
#pragma unroll
            for (int n = 0; n < 4; ++n) {
                acc[m][n] = __builtin_amdgcn_mfma_f32_16x16x32_bf16(afh[m], bfh[n], acc[m][n], 0, 0, 0);
                acc[m][n] = __builtin_amdgcn_mfma_f32_16x16x32_bf16(afl[m], bfh[n], acc[m][n], 0, 0, 0);
                acc[m][n] = __builtin_amdgcn_mfma_f32_16x16x32_bf16(afh[m], bfl[n], acc[m][n], 0, 0, 0);
            }
    }

    // epilogue: C/D layout col=lane&15, row=(lane>>4)*4+r
    const int orow  = i0 + wr * 64 + (lane >> 4) * 4;
    const int ocol0 = n0 + wc * 64 + (lane & 15);
#pragma unroll
    for (int n = 0; n < 4; ++n) {
        const int colg = ocol0 + n * 16;
        float bv = bias ? bias[colg] : 0.f;
#pragma unroll
        for (int m = 0; m < 4; ++m) {
#pragma unroll
            for (int r = 0; r < 4; ++r) {
                const int rowg = orow + m * 16 + r;
                float v = acc[m][n][r] + bv;
                if (ACT == 1) v = gelu_f(v);
                size_t off = (size_t)rowg * N + colg;
                if (SPLIT_OUT) {
                    ushort h = f2bf(v);
                    Chi[off] = h;
                    Clo[off] = f2bf(v - bf2f(h));
                } else {
                    C[off] = v;
                }
            }
        }
    }
}

// ------------- per-head projection -> bf16 hi/lo planes (b,h,s,m) -------------
__global__ __launch_bounds__(256)
void headproj_kernel(const float* __restrict__ X, int xstride, const float* __restrict__ Mk,
                     ushort* __restrict__ oh, ushort* __restrict__ ol) {
    __shared__ float Qs[64][65];
    __shared__ float Ms[64][68];
    const int s0 = blockIdx.x * 64;
    const int h  = blockIdx.y;
    const int b  = blockIdx.z;
    const int t  = threadIdx.x;
    const int tc = t & 15, tr = t >> 4;
    const float* xb = X + (size_t)(b * SEQ + s0) * xstride + h * 64;
    const float* mk = Mk + (size_t)h * 64 * 64;
#pragma unroll
    for (int i = 0; i < 4; ++i) {
        int e4  = t + i * 256;
        int row = e4 >> 4;
        int c4  = (e4 & 15) << 2;
        float4 q4 = *(const float4*)(xb + (size_t)row * xstride + c4);
        Qs[c4 + 0][row] = q4.x;
        Qs[c4 + 1][row] = q4.y;
        Qs[c4 + 2][row] = q4.z;
        Qs[c4 + 3][row] = q4.w;
        float4 m4 = *(const float4*)(mk + row * 64 + c4);
        *(float4*)&Ms[row][c4] = m4;
    }
    __syncthreads();
    float acc[4][4] = {};
#pragma unroll 16
    for (int kk = 0; kk < 64; ++kk) {
        float a0 = Qs[kk][tr * 4 + 0];
        float a1 = Qs[kk][tr * 4 + 1];
        float a2 = Qs[kk][tr * 4 + 2];
        float a3 = Qs[kk][tr * 4 + 3];
        float4 b4 = *(const float4*)&Ms[kk][tc * 4];
        acc[0][0] += a0 * b4.x; acc[0][1] += a0 * b4.y; acc[0][2] += a0 * b4.z; acc[0][3] += a0 * b4.w;
        acc[1][0] += a1 * b4.x; acc[1][1] += a1 * b4.y; acc[1][2] += a1 * b4.z; acc[1][3] += a1 * b4.w;
        acc[2][0] += a2 * b4.x; acc[2][1] += a2 * b4.y; acc[2][2] += a2 * b4.z; acc[2][3] += a2 * b4.w;
        acc[3][0] += a3 * b4.x; acc[3][1] += a3 * b4.y; acc[3][2] += a3 * b4.z; acc[3][3] += a3 * b4.w;
    }
    ushort* oph = oh + ((size_t)(b * NH + h) * SEQ + s0) * 64;
    ushort* opl = ol + ((size_t)(b * NH + h) * SEQ + s0) * 64;
#pragma unroll
    for (int i = 0; i < 4; ++i) {
        ushort4 h4, l4;
        h4.x = f2bf(acc[i][0]); l4.x = f2bf(acc[i][0] - bf2f(h4.x));
        h4.y = f2bf(acc[i][1]); l4.y = f2bf(acc[i][1] - bf2f(h4.y));
        h4.z = f2bf(acc[i][2]); l4.z = f2bf(acc[i][2] - bf2f(h4.z));
        h4.w = f2bf(acc[i][3]); l4.w = f2bf(acc[i][3] - bf2f(h4.w));
        *(ushort4*)(oph + (size_t)(tr * 4 + i) * 64 + tc * 4) = h4;
        *(ushort4*)(opl + (size_t)(tr * 4 + i) * 64 + tc * 4) = l4;
    }
}

// ------------- V slice: split + transpose -> vT hi/lo planes (b,h,d,s) -------------
__global__ __launch_bounds__(256)
void vsplitT_kernel(const float* __restrict__ qkv, ushort* __restrict__ vth,
                    ushort* __restrict__ vtl) {
    __shared__ float tile[64][65];
    const int s0 = blockIdx.x * 64;
    const int h  = blockIdx.y;
    const int b  = blockIdx.z;
    const int t  = threadIdx.x;
    const int r  = t >> 4;
    const int c4 = (t & 15) * 4;
    const float* src = qkv + (size_t)(b * SEQ + s0) * 3072 + 2048 + h * 64;
#pragma unroll
    for (int i = 0; i < 4; ++i) {
        int srow = r + i * 16;
        float4 v = *(const float4*)(src + (size_t)srow * 3072 + c4);
        tile[c4 + 0][srow] = v.x;
        tile[c4 + 1][srow] = v.y;
        tile[c4 + 2][srow] = v.z;
        tile[c4 + 3][srow] = v.w;
    }
    __syncthreads();
    const size_t obase = (size_t)(b * NH + h) * 64 * SEQ + s0;
#pragma unroll
    for (int i = 0; i < 4; ++i) {
        int d = r + i * 16;
        float a = tile[d][c4 + 0], bb = tile[d][c4 + 1];
        float c = tile[d][c4 + 2], dd = tile[d][c4 + 3];
        ushort4 h4, l4;
        h4.x = f2bf(a);  l4.x = f2bf(a - bf2f(h4.x));
        h4.y = f2bf(bb); l4.y = f2bf(bb - bf2f(h4.y));
        h4.z = f2bf(c);  l4.z = f2bf(c - bf2f(h4.z));
        h4.w = f2bf(dd); l4.w = f2bf(dd - bf2f(h4.w));
        *(ushort4*)&vth[obase + (size_t)d * SEQ + c4] = h4;
        *(ushort4*)&vtl[obase + (size_t)d * SEQ + c4] = l4;
    }
}

// ------------- MFMA flash attention: QK bf16x3, PV = P_hi x (V_hi + V_lo) -------------
// grid (SEQ/16, NH, BATCH), 64 threads = 1 wave owning 16 q-rows. R11 prefetch
// structure; P_lo plane dropped (error ~2e-3 abs, under slack): 40 MFMA/tile,
// half the P LDS traffic and f2bf work.
__global__ __launch_bounds__(64)
void attn_mfma(const ushort* __restrict__ qmh, const ushort* __restrict__ qml,
               const ushort* __restrict__ kmh, const ushort* __restrict__ kml,
               const ushort* __restrict__ vth, const ushort* __restrict__ vtl,
               ushort* __restrict__ ctx_hi, ushort* __restrict__ ctx_lo) {
    __shared__ ushort ph[1024];   // [16q x 64kv] hi, XOR-swizzled
    const int q0 = blockIdx.x * 16;
    const int h  = blockIdx.y;
    const int b  = blockIdx.z;
    const int lane = threadIdx.x;
    const int rg = lane >> 4;      // 0..3
    const int lc = lane & 15;
    const size_t bh = (size_t)b * NH + h;

    const ushort* qb_h = qmh + (bh * SEQ + q0 + lc) * 64 + rg * 8;
    const ushort* qb_l = qml + (bh * SEQ + q0 + lc) * 64 + rg * 8;
    bf16x8 qfh[2], qfl[2];
    qfh[0] = *(const bf16x8*)(qb_h);
    qfh[1] = *(const bf16x8*)(qb_h + 32);
    qfl[0] = *(const bf16x8*)(qb_l);
    qfl[1] = *(const bf16x8*)(qb_l + 32);

    const ushort* kb_h = kmh + (bh * SEQ + lc) * 64 + rg * 8;
    const ushort* kb_l = kml + (bh * SEQ + lc) * 64 + rg * 8;
    const ushort* vb_h = vth + (bh * 64 + lc) * SEQ + rg * 8;
    const ushort* vb_l = vtl + (bh * 64 + lc) * SEQ + rg * 8;

    f32x4 ctx[4];
#pragma unroll
    for (int n = 0; n < 4; ++n) { ctx[n][0] = 0.f; ctx[n][1] = 0.f; ctx[n][2] = 0.f; ctx[n][3] = 0.f; }
    float m_r[4] = { -INFINITY, -INFINITY, -INFINITY, -INFINITY };
    float l_r[4] = { 0.f, 0.f, 0.f, 0.f };

    // prefetch tile 0 K (hi+lo)
    bf16x8 kh[4][2], kl[4][2];
#pragma unroll
    for (int n = 0; n < 4; ++n) {
        kh[n][0] = *(const bf16x8*)(kb_h + (size_t)(16 * n) * 64);
        kh[n][1] = *(const bf16x8*)(kb_h + (size_t)(16 * n) * 64 + 32);
        kl[n][0] = *(const bf16x8*)(kb_l + (size_t)(16 * n) * 64);
        kl[n][1] = *(const bf16x8*)(kb_l + (size_t)(16 * n) * 64 + 32);
    }

    for (int kv0 = 0; kv0 < SEQ; kv0 += 64) {
        // ---- V_hi loads early: consumed only after softmax ----
        bf16x8 vh[4][2];
#pragma unroll
        for (int n = 0; n < 4; ++n) {
            vh[n][0] = *(const bf16x8*)(vb_h + (size_t)(16 * n) * SEQ + kv0);
            vh[n][1] = *(const bf16x8*)(vb_h + (size_t)(16 * n) * SEQ + kv0 + 32);
        }
        // ---- QK^T (bf16x3) with current-tile kh/kl ----
        f32x4 sacc[4];
#pragma unroll
        for (int n = 0; n < 4; ++n) { sacc[n][0] = 0.f; sacc[n][1] = 0.f; sacc[n][2] = 0.f; sacc[n][3] = 0.f; }
#pragma unroll
        for (int n = 0; n < 4; ++n) {
            sacc[n] = __builtin_amdgcn_mfma_f32_16x16x32_bf16(qfh[0], kh[n][0], sacc[n], 0, 0, 0);
            sacc[n] = __builtin_amdgcn_mfma_f32_16x16x32_bf16(qfh[1], kh[n][1], sacc[n], 0, 0, 0);
            sacc[n] = __builtin_amdgcn_mfma_f32_16x16x32_bf16(qfl[0], kh[n][0], sacc[n], 0, 0, 0);
            sacc[n] = __builtin_amdgcn_mfma_f32_16x16x32_bf16(qfl[1], kh[n][1], sacc[n], 0, 0, 0);
            sacc[n] = __builtin_amdgcn_mfma_f32_16x16x32_bf16(qfh[0], kl[n][0], sacc[n], 0, 0, 0);
            sacc[n] = __builtin_amdgcn_mfma_f32_16x16x32_bf16(qfh[1], kl[n][1], sacc[n], 0, 0, 0);
        }
        // ---- prefetch next tile's K (hi+lo): latency hidden under softmax+PV ----
        if (kv0 + 64 < SEQ) {
            const size_t nb = (size_t)(kv0 + 64) * 64;
#pragma unroll
            for (int n = 0; n < 4; ++n) {
                kh[n][0] = *(const bf16x8*)(kb_h + nb + (size_t)(16 * n) * 64);
                kh[n][1] = *(const bf16x8*)(kb_h + nb + (size_t)(16 * n) * 64 + 32);
                kl[n][0] = *(const bf16x8*)(kb_l + nb + (size_t)(16 * n) * 64);
                kl[n][1] = *(const bf16x8*)(kb_l + nb + (size_t)(16 * n) * 64 + 32);
            }
        }
        // ---- online softmax (per q-row rg*4+r; reduce over 16-lane group) ----
#pragma unroll
        for (int r = 0; r < 4; ++r) {
            float s0 = sacc[0][r] * 0.125f;
            float s1 = sacc[1][r] * 0.125f;
            float s2 = sacc[2][r] * 0.125f;
            float s3 = sacc[3][r] * 0.125f;
            float pm = fmaxf(fmaxf(s0, s1), fmaxf(s2, s3));
            pm = fmaxf(pm, __shfl_xor(pm, 1));
            pm = fmaxf(pm, __shfl_xor(pm, 2));
            pm = fmaxf(pm, __shfl_xor(pm, 4));
            pm = fmaxf(pm, __shfl_xor(pm, 8));
            float mnew  = fmaxf(m_r[r], pm);
            float alpha = __expf(m_r[r] - mnew);
            m_r[r] = mnew;
            float p0 = __expf(s0 - mnew);
            float p1 = __expf(s1 - mnew);
            float p2 = __expf(s2 - mnew);
            float p3 = __expf(s3 - mnew);
            float rs = p0 + p1 + p2 + p3;
            rs += __shfl_xor(rs, 1);
            rs += __shfl_xor(rs, 2);
            rs += __shfl_xor(rs, 4);
            rs += __shfl_xor(rs, 8);
            l_r[r] = l_r[r] * alpha + rs;
            ctx[0][r] *= alpha; ctx[1][r] *= alpha; ctx[2][r] *= alpha; ctx[3][r] *= alpha;
            const int q = rg * 4 + r;
            const int swz = (q & 7) << 3;
            const int rowb = q * 64;
            ph[(rowb + lc)      ^ swz] = f2bf(p0);
            ph[(rowb + lc + 16) ^ swz] = f2bf(p1);
            ph[(rowb + lc + 32) ^ swz] = f2bf(p2);
            ph[(rowb + lc + 48) ^ swz] = f2bf(p3);
        }
        // ---- V_lo loads: consumed after the 8 hi-PV MFMAs ----
        bf16x8 vl[4][2];
#pragma unroll
        for (int n = 0; n < 4; ++n) {
            vl[n][0] = *(const bf16x8*)(vb_l + (size_t)(16 * n) * SEQ + kv0);
            vl[n][1] = *(const bf16x8*)(vb_l + (size_t)(16 * n) * SEQ + kv0 + 32);
        }
        // ---- PV: P_hi x (V_hi + V_lo); P frags via wave-private LDS transpose ----
        bf16x8 pah[2];
        {
            const int swz = (lc & 7) << 3;
            pah[0] = *(const bf16x8*)&ph[(lc * 64 + rg * 8)      ^ swz];
            pah[1] = *(const bf16x8*)&ph[(lc * 64 + rg * 8 + 32) ^ swz];
        }
#pragma unroll
        for (int n = 0; n < 4; ++n) {
            ctx[n] = __builtin_amdgcn_mfma_f32_16x16x32_bf16(pah[0], vh[n][0], ctx[n], 0, 0, 0);
            ctx[n] = __builtin_amdgcn_mfma_f32_16x16x32_bf16(pah[1], vh[n][1], ctx[n], 0, 0, 0);
        }
#pragma unroll
        for (int n = 0; n < 4; ++n) {
            ctx[n] = __builtin_amdgcn_mfma_f32_16x16x32_bf16(pah[0], vl[n][0], ctx[n], 0, 0, 0);
            ctx[n] = __builtin_amdgcn_mfma_f32_16x16x32_bf16(pah[1], vl[n][1], ctx[n], 0, 0, 0);
        }
    }
    // ---- epilogue: normalize, write ctx hi/lo planes at (b,s,h*64+d) ----
#pragma unroll
    for (int r = 0; r < 4; ++r) {
        float inv = 1.0f / l_r[r];
        const int q = q0 + rg * 4 + r;
        size_t base = ((size_t)b * SEQ + q) * DMODEL + h * 64 + lc;
#pragma unroll
        for (int n = 0; n < 4; ++n) {
            float o = ctx[n][r] * inv;
            ushort hh = f2bf(o);
            ctx_hi[base + 16 * n] = hh;
            ctx_lo[base + 16 * n] = f2bf(o - bf2f(hh));
        }
    }
}

// ------------- fused residual + LayerNorm (+ optional bf16 hi/lo split of output) -------------
__global__ __launch_bounds__(256)
void ln_kernel(const float* __restrict__ X, const float* __restrict__ R,
               const float* __restrict__ gw, const float* __restrict__ bw,
               float* __restrict__ out, ushort* __restrict__ ohi, ushort* __restrict__ olo) {
    __shared__ float red[8];
    const int i = blockIdx.x;
    const int t = threadIdx.x;
    const float* xp = X + (size_t)i * DMODEL;
    const float* rp = R + (size_t)i * DMODEL;
    float4 xv = *(const float4*)(xp + t * 4);
    float4 rv = *(const float4*)(rp + t * 4);
    float v0 = xv.x + rv.x, v1 = xv.y + rv.y, v2 = xv.z + rv.z, v3 = xv.w + rv.w;
    float sum = v0 + v1 + v2 + v3;
    float sq  = v0 * v0 + v1 * v1 + v2 * v2 + v3 * v3;
#pragma unroll
    for (int off = 32; off > 0; off >>= 1) {
        sum += __shfl_down(sum, off, 64);
        sq  += __shfl_down(sq,  off, 64);
    }
    int wid = t >> 6;
    if ((t & 63) == 0) { red[wid] = sum; red[4 + wid] = sq; }
    __syncthreads();
    sum = red[0] + red[1] + red[2] + red[3];
    sq  = red[4] + red[5] + red[6] + red[7];
    float mu   = sum * (1.0f / DMODEL);
    float var  = sq * (1.0f / DMODEL) - mu * mu;
    float rstd = rsqrtf(var + 1e-5f);
    float4 gv = *(const float4*)(gw + t * 4);
    float4 bv = *(const float4*)(bw + t * 4);
    float4 o;
    o.x = (v0 - mu) * rstd * gv.x + bv.x;
    o.y = (v1 - mu) * rstd * gv.y + bv.y;
    o.z = (v2 - mu) * rstd * gv.z + bv.z;
    o.w = (v3 - mu) * rstd * gv.w + bv.w;
    *(float4*)(out + (size_t)i * DMODEL + t * 4) = o;
    if (ohi) {
        ushort4 h, l;
        h.x = f2bf(o.x); l.x = f2bf(o.x - bf2f(h.x));
        h.y = f2bf(o.y); l.y = f2bf(o.y - bf2f(h.y));
        h.z = f2bf(o.z); l.z = f2bf(o.z - bf2f(h.z));
        h.w = f2bf(o.w); l.w = f2bf(o.w - bf2f(h.w));
        size_t off = (size_t)i * DMODEL + t * 4;
        *(ushort4*)&ohi[off] = h;
        *(ushort4*)&olo[off] = l;
    }
}

extern "C" void kernel_launch(void* const* d_in, const int* in_sizes, int n_in,
                              void* d_out, int out_size, void* d_ws, size_t ws_size,
                              hipStream_t stream) {
    const float* x   = (const float*)d_in[0];
    const float* Wq  = (const float*)d_in[1];
    const float* Wk  = (const float*)d_in[2];
    const float* Wv  = (const float*)d_in[3];
    const float* Wo  = (const float*)d_in[4];
    const float* Mk  = (const float*)d_in[5];
    const float* g1  = (const float*)d_in[6];
    const float* bl1 = (const float*)d_in[7];
    const float* g2  = (const float*)d_in[8];
    const float* bl2 = (const float*)d_in[9];
    const float* W1  = (const float*)d_in[10];
    const float* bf1 = (const float*)d_in[11];
    const float* W2  = (const float*)d_in[12];
    const float* bf2 = (const float*)d_in[13];
    float* out = (float*)d_out;
    char* wsb  = (char*)d_ws;

    const size_t MB = 1024 * 1024;
    // ---- workspace layout, peak 192 MB (lifetime-overlapped; validated R8/R11) ----
    float*  qkv   = (float*)(wsb + 0 * MB);
    ushort* qmh   = (ushort*)(wsb + 48 * MB);
    ushort* qml   = (ushort*)(wsb + 56 * MB);
    ushort* kmh   = (ushort*)(wsb + 64 * MB);
    ushort* kml   = (ushort*)(wsb + 72 * MB);
    ushort* vth   = (ushort*)(wsb + 80 * MB);
    ushort* vtl   = (ushort*)(wsb + 88 * MB);
    ushort* x_hi  = (ushort*)(wsb + 96 * MB);
    ushort* x_lo  = (ushort*)(wsb + 104 * MB);
    ushort* ctx_hi = x_hi;                       // x planes dead after QKV
    ushort* ctx_lo = x_lo;
    float*  wo_out = (float*)(wsb + 112 * MB);
    float*  ff2    = wo_out;                     // wo_out dead after LN1
    float*  y      = (float*)(wsb + 128 * MB);
    ushort* y_hi   = (ushort*)(wsb + 144 * MB);
    ushort* y_lo   = (ushort*)(wsb + 152 * MB);
    ushort* wqkvT_hi = (ushort*)(wsb + 160 * MB);   // 3072x1024 = 6 MB
    ushort* wqkvT_lo = (ushort*)(wsb + 166 * MB);
    ushort* woT_hi   = (ushort*)(wsb + 172 * MB);   // 2 MB
    ushort* woT_lo   = (ushort*)(wsb + 174 * MB);
    ushort* w1T_hi   = (ushort*)(wsb + 176 * MB);   // 8 MB
    ushort* w1T_lo   = (ushort*)(wsb + 184 * MB);
    ushort* w2T_hi   = (ushort*)(wsb + 64 * MB);    // over dead km planes (split after attn)
    ushort* w2T_lo   = (ushort*)(wsb + 72 * MB);
    ushort* h1_hi    = (ushort*)(wsb + 0 * MB);     // 32 MB over dead qkv
    ushort* h1_lo    = (ushort*)(wsb + 32 * MB);

    dim3 blk(256);
    dim3 hgrid(SEQ / 64, NH, BATCH);
    // --- weight prep (W2 deferred until km planes are dead) ---
    splitT_kernel<<<dim3(16, 16), blk, 0, stream>>>(Wq, wqkvT_hi, wqkvT_lo, DMODEL, DMODEL);
    splitT_kernel<<<dim3(16, 16), blk, 0, stream>>>(Wk, wqkvT_hi + (size_t)1024 * 1024, wqkvT_lo + (size_t)1024 * 1024, DMODEL, DMODEL);
    splitT_kernel<<<dim3(16, 16), blk, 0, stream>>>(Wv, wqkvT_hi + (size_t)2048 * 1024, wqkvT_lo + (size_t)2048 * 1024, DMODEL, DMODEL);
    splitT_kernel<<<dim3(16, 16), blk, 0, stream>>>(Wo, woT_hi, woT_lo, DMODEL, DMODEL);
    splitT_kernel<<<dim3(64, 16), blk, 0, stream>>>(W1, w1T_hi, w1T_lo, DMODEL, FDIM);
    // --- x split + fused QKV projection ---
    splitA_kernel<<<dim3(4096), blk, 0, stream>>>(x, x_hi, x_lo, NROWS * DMODEL / 4);
    mfma_gemm<0, 0><<<dim3(24, 32), blk, 0, stream>>>(x_hi, x_lo, wqkvT_hi, wqkvT_lo,
                                                      nullptr, qkv, nullptr, nullptr, DMODEL, 3072);
    // --- memory-key projections -> bf16 planes ---
    headproj_kernel<<<hgrid, blk, 0, stream>>>(qkv + 0,    3072, Mk, qmh, qml);
    headproj_kernel<<<hgrid, blk, 0, stream>>>(qkv + 1024, 3072, Mk, kmh, kml);
    // --- V split+transpose -> (b,h,d,s) planes ---
    vsplitT_kernel<<<hgrid, blk, 0, stream>>>(qkv, vth, vtl);
    // --- MFMA flash attention (1-wave blocks) -> ctx planes ---
    attn_mfma<<<dim3(SEQ / 16, NH, BATCH), dim3(64), 0, stream>>>(qmh, qml, kmh, kml, vth, vtl, ctx_hi, ctx_lo);
    // --- W2 split (km planes now dead) ---
    splitT_kernel<<<dim3(16, 64), blk, 0, stream>>>(W2, w2T_hi, w2T_lo, FDIM, DMODEL);
    // --- Wo projection ---
    mfma_gemm<0, 0><<<dim3(8, 32), blk, 0, stream>>>(ctx_hi, ctx_lo, woT_hi, woT_lo,
                                                     nullptr, wo_out, nullptr, nullptr, DMODEL, DMODEL);
    // --- LN1 (+ split of y) ---
    ln_kernel<<<dim3(NROWS), blk, 0, stream>>>(x, wo_out, g1, bl1, y, y_hi, y_lo);
    // --- FFN1: bias + GELU + split fused ---
    mfma_gemm<1, 1><<<dim3(32, 32), blk, 0, stream>>>(y_hi, y_lo, w1T_hi, w1T_lo,
                                                      bf1, nullptr, h1_hi, h1_lo, DMODEL, FDIM);
    // --- FFN2 ---
    mfma_gemm<0, 0><<<dim3(8, 32), blk, 0, stream>>>(h1_hi, h1_lo, w2T_hi, w2T_lo,
                                                     bf2, ff2, nullptr, nullptr, FDIM, DMODEL);
    // --- LN2 -> out ---
    ln_kernel<<<dim3(NROWS), blk, 0, stream>>>(y, ff2, g2, bl2, out, nullptr, nullptr);
}